// Round 2
// baseline (16193.799 us; speedup 1.0000x reference)
//
#include <hip/hip_runtime.h>

#define EPS 1e-5f

// One thread per output row; 32 fp32 accumulators (Co=32) kept in VGPRs
// (launch_bounds(256,2) -> 256-VGPR cap; round-1's default spilled at 36 VGPRs).
// Branchless taps: invalid neighbor -> load row 0, multiply by 0. This lets the
// compiler software-pipeline gathers across taps (#pragma unroll 2).
// W addressing is wave-uniform (k,ci,co uniform) -> scalar loads, FMA w/ SGPR src.
template <int CI, int K>
__global__ __launch_bounds__(256, 2) void conv_kernel(
    const float* __restrict__ x, const int* __restrict__ nbr,
    const float* __restrict__ W, float* __restrict__ y,
    float* __restrict__ stats, int N)
{
    int row = blockIdx.x * 256 + threadIdx.x;
    bool active = row < N;
    int r = active ? row : 0;

    int idxs[K];
#pragma unroll
    for (int k = 0; k < K; ++k) {
        int idx = nbr[(long)k * N + r];
        idxs[k] = active ? idx : -1;   // inactive rows contribute zero everywhere
    }

    float acc[32];
#pragma unroll
    for (int co = 0; co < 32; ++co) acc[co] = 0.0f;

#pragma unroll 2
    for (int k = 0; k < K; ++k) {
        int idx = idxs[k];
        float s = (idx >= 0) ? 1.0f : 0.0f;
        const float4* xr = (const float4*)(x + (long)(idx >= 0 ? idx : 0) * CI);
        float xv[CI];
#pragma unroll
        for (int c4 = 0; c4 < CI / 4; ++c4) {
            float4 v = xr[c4];
            xv[c4 * 4 + 0] = v.x * s;
            xv[c4 * 4 + 1] = v.y * s;
            xv[c4 * 4 + 2] = v.z * s;
            xv[c4 * 4 + 3] = v.w * s;
        }
        const float* Wk = W + k * CI * 32;
#pragma unroll
        for (int ci = 0; ci < CI; ++ci) {
#pragma unroll
            for (int co = 0; co < 32; ++co)
                acc[co] = fmaf(xv[ci], Wk[ci * 32 + co], acc[co]);
        }
    }

    if (active) {
        float4* yr = (float4*)(y + (long)row * 32);
#pragma unroll
        for (int c4 = 0; c4 < 8; ++c4)
            yr[c4] = make_float4(acc[c4 * 4 + 0], acc[c4 * 4 + 1],
                                 acc[c4 * 4 + 2], acc[c4 * 4 + 3]);
    }

    // BN stats: per-wave butterfly then one atomic pair per wave per channel.
    // Inactive rows hold acc==0 and contribute nothing.
#pragma unroll
    for (int co = 0; co < 32; ++co) {
        float s = acc[co];
        float q = s * s;
#pragma unroll
        for (int off = 32; off >= 1; off >>= 1) {
            s += __shfl_down(s, off);
            q += __shfl_down(q, off);
        }
        if ((threadIdx.x & 63) == 0) {
            atomicAdd(&stats[co], s);
            atomicAdd(&stats[32 + co], q);
        }
    }
}

// Elementwise BN (+optional residual) + ReLU, float4-vectorized. In-place safe.
__global__ __launch_bounds__(256) void bn_relu_kernel(
    const float* __restrict__ y, const float* __restrict__ stats,
    const float* __restrict__ gamma, const float* __restrict__ beta,
    const float* __restrict__ resid, float* __restrict__ out, int N)
{
    long i = (long)blockIdx.x * 256 + threadIdx.x;   // index in float4 units
    long total4 = (long)N * 8;
    if (i >= total4) return;
    int c4 = (int)(i & 7);                           // float4 group within row
    float inv_n = 1.0f / (float)N;
    float4 v = ((const float4*)y)[i];
    float4 o;
#pragma unroll
    for (int j = 0; j < 4; ++j) {
        int co = c4 * 4 + j;
        float mu = stats[co] * inv_n;
        float var = stats[32 + co] * inv_n - mu * mu;
        float scale = rsqrtf(var + EPS) * gamma[co];
        float val = ((&v.x)[j] - mu) * scale + beta[co];
        (&o.x)[j] = val;
    }
    if (resid) {
        float4 rv = ((const float4*)resid)[i];
        o.x += rv.x; o.y += rv.y; o.z += rv.z; o.w += rv.w;
    }
    o.x = fmaxf(o.x, 0.0f); o.y = fmaxf(o.y, 0.0f);
    o.z = fmaxf(o.z, 0.0f); o.w = fmaxf(o.w, 0.0f);
    ((float4*)out)[i] = o;
}

extern "C" void kernel_launch(void* const* d_in, const int* in_sizes, int n_in,
                              void* d_out, int out_size, void* d_ws, size_t ws_size,
                              hipStream_t stream)
{
    const float* vf   = (const float*)d_in[0];
    const float* Ws1  = (const float*)d_in[1];
    const float* Ws2  = (const float*)d_in[2];
    const float* Wd   = (const float*)d_in[3];
    const float* Wr1a = (const float*)d_in[4];
    const float* Wr1b = (const float*)d_in[5];
    const float* Wr2a = (const float*)d_in[6];
    const float* Wr2b = (const float*)d_in[7];
    const float* gam  = (const float*)d_in[8];
    const float* bet  = (const float*)d_in[9];
    const int* nbr0   = (const int*)d_in[10];
    const int* down1  = (const int*)d_in[11];
    const int* nbr1   = (const int*)d_in[12];

    int N0 = in_sizes[0] / 4;
    int N1 = in_sizes[11] / 8;

    float* bufA  = (float*)d_ws;                 // N0*32 floats
    float* bufB  = bufA + (size_t)N0 * 32;       // N0*32 floats
    float* stats = bufB + (size_t)N0 * 32;       // 7*64 floats
    float* out   = (float*)d_out;                // N1*32 floats (also raw-conv scratch)

    hipMemsetAsync(stats, 0, 7 * 64 * sizeof(float), stream);

    auto cgrid = [](int n) { return dim3((unsigned)((n + 255) / 256)); };
    auto bgrid = [](long n) { return dim3((unsigned)((n * 8 + 255) / 256)); };

    // stem1: vf -> bufA
    conv_kernel<4, 27><<<cgrid(N0), 256, 0, stream>>>(vf, nbr0, Ws1, bufA, stats + 0 * 64, N0);
    bn_relu_kernel<<<bgrid(N0), 256, 0, stream>>>(bufA, stats + 0 * 64, gam + 0, bet + 0, nullptr, bufA, N0);
    // stem2: bufA -> bufB
    conv_kernel<32, 27><<<cgrid(N0), 256, 0, stream>>>(bufA, nbr0, Ws2, bufB, stats + 1 * 64, N0);
    bn_relu_kernel<<<bgrid(N0), 256, 0, stream>>>(bufB, stats + 1 * 64, gam + 32, bet + 32, nullptr, bufB, N0);
    // down: bufB -> bufA (x1)
    conv_kernel<32, 8><<<cgrid(N1), 256, 0, stream>>>(bufB, down1, Wd, bufA, stats + 2 * 64, N1);
    bn_relu_kernel<<<bgrid(N1), 256, 0, stream>>>(bufA, stats + 2 * 64, gam + 64, bet + 64, nullptr, bufA, N1);
    // r1a: bufA -> bufB (h)
    conv_kernel<32, 27><<<cgrid(N1), 256, 0, stream>>>(bufA, nbr1, Wr1a, bufB, stats + 3 * 64, N1);
    bn_relu_kernel<<<bgrid(N1), 256, 0, stream>>>(bufB, stats + 3 * 64, gam + 96, bet + 96, nullptr, bufB, N1);
    // r1b: bufB -> d_out (raw), then x1' = relu(bn(d_out) + bufA) -> bufA
    conv_kernel<32, 27><<<cgrid(N1), 256, 0, stream>>>(bufB, nbr1, Wr1b, out, stats + 4 * 64, N1);
    bn_relu_kernel<<<bgrid(N1), 256, 0, stream>>>(out, stats + 4 * 64, gam + 128, bet + 128, bufA, bufA, N1);
    // r2a: bufA -> bufB (h)
    conv_kernel<32, 27><<<cgrid(N1), 256, 0, stream>>>(bufA, nbr1, Wr2a, bufB, stats + 5 * 64, N1);
    bn_relu_kernel<<<bgrid(N1), 256, 0, stream>>>(bufB, stats + 5 * 64, gam + 160, bet + 160, nullptr, bufB, N1);
    // r2b: bufB -> d_out (raw), then out = relu(bn(d_out) + bufA) -> d_out
    conv_kernel<32, 27><<<cgrid(N1), 256, 0, stream>>>(bufB, nbr1, Wr2b, out, stats + 6 * 64, N1);
    bn_relu_kernel<<<bgrid(N1), 256, 0, stream>>>(out, stats + 6 * 64, gam + 192, bet + 192, bufA, out, N1);
}

// Round 3
// 15646.936 us; speedup vs baseline: 1.0350x; 1.0350x over previous
//
#include <hip/hip_runtime.h>

#define EPS 1e-5f

// One thread per output row; 32 fp32 accumulators (Co=32) in VGPRs.
// CRITICAL (round-2 lesson): no index arrays, no partially-unrolled loops over
// register arrays -> everything indexable is either fully unrolled (acc, ci)
// or loaded in-loop (idx). Live set ~70 VGPRs; launch_bounds(256,4) caps at 128.
// Branchless taps: invalid neighbor -> gather row 0, scale by 0 (lets gathers
// pipeline; at these densities >=1 lane/wave is valid ~98% of the time anyway).
// W addressing is wave-uniform (k uniform, ci/co unrolled) -> scalar s_loads.
template <int CI, int K>
__global__ __launch_bounds__(256, 4) void conv_kernel(
    const float* __restrict__ x, const int* __restrict__ nbr,
    const float* __restrict__ W, float* __restrict__ y,
    float* __restrict__ stats, int N)
{
    int row = blockIdx.x * 256 + threadIdx.x;
    bool active = row < N;
    int r = active ? row : 0;

    float acc[32];
#pragma unroll
    for (int co = 0; co < 32; ++co) acc[co] = 0.0f;

#pragma unroll 3
    for (int k = 0; k < K; ++k) {
        int idx = nbr[(long)k * N + r];
        if (!active) idx = -1;
        float s = (idx >= 0) ? 1.0f : 0.0f;
        const float4* xr = (const float4*)(x + (long)(idx >= 0 ? idx : 0) * CI);
        const float* Wk = W + k * CI * 32;
#pragma unroll
        for (int c4 = 0; c4 < CI / 4; ++c4) {
            float4 v = xr[c4];
            v.x *= s; v.y *= s; v.z *= s; v.w *= s;
#pragma unroll
            for (int co = 0; co < 32; ++co)
                acc[co] = fmaf(v.x, Wk[(c4 * 4 + 0) * 32 + co], acc[co]);
#pragma unroll
            for (int co = 0; co < 32; ++co)
                acc[co] = fmaf(v.y, Wk[(c4 * 4 + 1) * 32 + co], acc[co]);
#pragma unroll
            for (int co = 0; co < 32; ++co)
                acc[co] = fmaf(v.z, Wk[(c4 * 4 + 2) * 32 + co], acc[co]);
#pragma unroll
            for (int co = 0; co < 32; ++co)
                acc[co] = fmaf(v.w, Wk[(c4 * 4 + 3) * 32 + co], acc[co]);
        }
    }

    if (active) {
        float4* yr = (float4*)(y + (long)row * 32);
#pragma unroll
        for (int c4 = 0; c4 < 8; ++c4)
            yr[c4] = make_float4(acc[c4 * 4 + 0], acc[c4 * 4 + 1],
                                 acc[c4 * 4 + 2], acc[c4 * 4 + 3]);
    }

    // BN stats: per-wave butterfly then one atomic pair per wave per channel.
    // Inactive rows hold acc==0 and contribute nothing.
#pragma unroll
    for (int co = 0; co < 32; ++co) {
        float s = acc[co];
        float q = s * s;
#pragma unroll
        for (int off = 32; off >= 1; off >>= 1) {
            s += __shfl_down(s, off);
            q += __shfl_down(q, off);
        }
        if ((threadIdx.x & 63) == 0) {
            atomicAdd(&stats[co], s);
            atomicAdd(&stats[32 + co], q);
        }
    }
}

// Elementwise BN (+optional residual) + ReLU, float4-vectorized. In-place safe.
__global__ __launch_bounds__(256) void bn_relu_kernel(
    const float* __restrict__ y, const float* __restrict__ stats,
    const float* __restrict__ gamma, const float* __restrict__ beta,
    const float* __restrict__ resid, float* __restrict__ out, int N)
{
    long i = (long)blockIdx.x * 256 + threadIdx.x;   // index in float4 units
    long total4 = (long)N * 8;
    if (i >= total4) return;
    int c4 = (int)(i & 7);                           // float4 group within row
    float inv_n = 1.0f / (float)N;
    float4 v = ((const float4*)y)[i];
    float4 o;
#pragma unroll
    for (int j = 0; j < 4; ++j) {
        int co = c4 * 4 + j;
        float mu = stats[co] * inv_n;
        float var = stats[32 + co] * inv_n - mu * mu;
        float scale = rsqrtf(var + EPS) * gamma[co];
        (&o.x)[j] = ((&v.x)[j] - mu) * scale + beta[co];
    }
    if (resid) {
        float4 rv = ((const float4*)resid)[i];
        o.x += rv.x; o.y += rv.y; o.z += rv.z; o.w += rv.w;
    }
    o.x = fmaxf(o.x, 0.0f); o.y = fmaxf(o.y, 0.0f);
    o.z = fmaxf(o.z, 0.0f); o.w = fmaxf(o.w, 0.0f);
    ((float4*)out)[i] = o;
}

extern "C" void kernel_launch(void* const* d_in, const int* in_sizes, int n_in,
                              void* d_out, int out_size, void* d_ws, size_t ws_size,
                              hipStream_t stream)
{
    const float* vf   = (const float*)d_in[0];
    const float* Ws1  = (const float*)d_in[1];
    const float* Ws2  = (const float*)d_in[2];
    const float* Wd   = (const float*)d_in[3];
    const float* Wr1a = (const float*)d_in[4];
    const float* Wr1b = (const float*)d_in[5];
    const float* Wr2a = (const float*)d_in[6];
    const float* Wr2b = (const float*)d_in[7];
    const float* gam  = (const float*)d_in[8];
    const float* bet  = (const float*)d_in[9];
    const int* nbr0   = (const int*)d_in[10];
    const int* down1  = (const int*)d_in[11];
    const int* nbr1   = (const int*)d_in[12];

    int N0 = in_sizes[0] / 4;
    int N1 = in_sizes[11] / 8;

    float* bufA  = (float*)d_ws;                 // N0*32 floats
    float* bufB  = bufA + (size_t)N0 * 32;       // N0*32 floats
    float* stats = bufB + (size_t)N0 * 32;       // 7*64 floats
    float* out   = (float*)d_out;                // N1*32 floats (also raw-conv scratch)

    hipMemsetAsync(stats, 0, 7 * 64 * sizeof(float), stream);

    auto cgrid = [](int n) { return dim3((unsigned)((n + 255) / 256)); };
    auto bgrid = [](long n) { return dim3((unsigned)((n * 8 + 255) / 256)); };

    // stem1: vf -> bufA
    conv_kernel<4, 27><<<cgrid(N0), 256, 0, stream>>>(vf, nbr0, Ws1, bufA, stats + 0 * 64, N0);
    bn_relu_kernel<<<bgrid(N0), 256, 0, stream>>>(bufA, stats + 0 * 64, gam + 0, bet + 0, nullptr, bufA, N0);
    // stem2: bufA -> bufB
    conv_kernel<32, 27><<<cgrid(N0), 256, 0, stream>>>(bufA, nbr0, Ws2, bufB, stats + 1 * 64, N0);
    bn_relu_kernel<<<bgrid(N0), 256, 0, stream>>>(bufB, stats + 1 * 64, gam + 32, bet + 32, nullptr, bufB, N0);
    // down: bufB -> bufA (x1)
    conv_kernel<32, 8><<<cgrid(N1), 256, 0, stream>>>(bufB, down1, Wd, bufA, stats + 2 * 64, N1);
    bn_relu_kernel<<<bgrid(N1), 256, 0, stream>>>(bufA, stats + 2 * 64, gam + 64, bet + 64, nullptr, bufA, N1);
    // r1a: bufA -> bufB (h)
    conv_kernel<32, 27><<<cgrid(N1), 256, 0, stream>>>(bufA, nbr1, Wr1a, bufB, stats + 3 * 64, N1);
    bn_relu_kernel<<<bgrid(N1), 256, 0, stream>>>(bufB, stats + 3 * 64, gam + 96, bet + 96, nullptr, bufB, N1);
    // r1b: bufB -> d_out (raw), then x1' = relu(bn(d_out) + bufA) -> bufA
    conv_kernel<32, 27><<<cgrid(N1), 256, 0, stream>>>(bufB, nbr1, Wr1b, out, stats + 4 * 64, N1);
    bn_relu_kernel<<<bgrid(N1), 256, 0, stream>>>(out, stats + 4 * 64, gam + 128, bet + 128, bufA, bufA, N1);
    // r2a: bufA -> bufB (h)
    conv_kernel<32, 27><<<cgrid(N1), 256, 0, stream>>>(bufA, nbr1, Wr2a, bufB, stats + 5 * 64, N1);
    bn_relu_kernel<<<bgrid(N1), 256, 0, stream>>>(bufB, stats + 5 * 64, gam + 160, bet + 160, nullptr, bufB, N1);
    // r2b: bufB -> d_out (raw), then out = relu(bn(d_out) + bufA) -> d_out
    conv_kernel<32, 27><<<cgrid(N1), 256, 0, stream>>>(bufB, nbr1, Wr2b, out, stats + 6 * 64, N1);
    bn_relu_kernel<<<bgrid(N1), 256, 0, stream>>>(out, stats + 6 * 64, gam + 192, bet + 192, bufA, out, N1);
}

// Round 4
// 15513.483 us; speedup vs baseline: 1.0439x; 1.0086x over previous
//
#include <hip/hip_runtime.h>

#define EPS 1e-5f

// ---- helpers: everything is named scalars/float4s -- NO private arrays ----
// (rounds 1-3 lesson: float acc[32] gets demoted to scratch by the compiler
//  regardless of unroll pragmas; VGPR_Count=32/36/80 + 260-360MB scratch
//  FETCH proved it. Named float4s cannot be demoted.)

__device__ __forceinline__ float4 fma4(float s, float4 w, float4 a) {
    a.x = fmaf(s, w.x, a.x);
    a.y = fmaf(s, w.y, a.y);
    a.z = fmaf(s, w.z, a.z);
    a.w = fmaf(s, w.w, a.w);
    return a;
}

__device__ __forceinline__ float4 mul4(float4 v, float s) {
    v.x *= s; v.y *= s; v.z *= s; v.w *= s;
    return v;
}

__device__ __forceinline__ float4 add4(float4 v, float4 w) {
    v.x += w.x; v.y += w.y; v.z += w.z; v.w += w.w;
    return v;
}

__device__ __forceinline__ float4 relu4(float4 v) {
    v.x = fmaxf(v.x, 0.0f); v.y = fmaxf(v.y, 0.0f);
    v.z = fmaxf(v.z, 0.0f); v.w = fmaxf(v.w, 0.0f);
    return v;
}

// Per-channel BN-stat reduction: 64-lane butterfly on a scalar, one atomic
// pair per wave. Scalar v only -- no arrays.
__device__ __forceinline__ void red_one(float v, float* s_dst, float* q_dst, bool lead) {
    float s = v, q = v * v;
#pragma unroll
    for (int off = 32; off >= 1; off >>= 1) {
        s += __shfl_down(s, off);
        q += __shfl_down(q, off);
    }
    if (lead) { atomicAdd(s_dst, s); atomicAdd(q_dst, q); }
}

// One FMA step: one input channel value xs against W row (32 outputs = 8 float4).
// W address: uniform (k loop-uniform, ci/co compile-time) -> scalar-load eligible.
#define STEP4(xs, ci)                         \
    do {                                      \
        a0 = fma4(xs, Wk4[(ci) * 8 + 0], a0); \
        a1 = fma4(xs, Wk4[(ci) * 8 + 1], a1); \
        a2 = fma4(xs, Wk4[(ci) * 8 + 2], a2); \
        a3 = fma4(xs, Wk4[(ci) * 8 + 3], a3); \
        a4 = fma4(xs, Wk4[(ci) * 8 + 4], a4); \
        a5 = fma4(xs, Wk4[(ci) * 8 + 5], a5); \
        a6 = fma4(xs, Wk4[(ci) * 8 + 6], a6); \
        a7 = fma4(xs, Wk4[(ci) * 8 + 7], a7); \
    } while (0)

// One float4 chunk of the gathered input row (4 input channels).
#define CHUNK(c)                              \
    do {                                      \
        float4 xv = mul4(xr[c], s);           \
        STEP4(xv.x, (c) * 4 + 0);             \
        STEP4(xv.y, (c) * 4 + 1);             \
        STEP4(xv.z, (c) * 4 + 2);             \
        STEP4(xv.w, (c) * 4 + 3);             \
    } while (0)

// One thread per output row; 32 accumulators as 8 named float4s.
// Branchless taps: invalid neighbor -> gather row 0, scale 0.
template <int CI, int K>
__global__ __launch_bounds__(256, 3) void conv_kernel(
    const float* __restrict__ x, const int* __restrict__ nbr,
    const float* __restrict__ W, float* __restrict__ y,
    float* __restrict__ stats, int N)
{
    int row = blockIdx.x * 256 + threadIdx.x;
    bool active = row < N;
    int r = active ? row : 0;

    float4 a0 = make_float4(0.f, 0.f, 0.f, 0.f), a1 = a0, a2 = a0, a3 = a0,
           a4 = a0, a5 = a0, a6 = a0, a7 = a0;

#pragma unroll 1
    for (int k = 0; k < K; ++k) {
        int idx = nbr[(long)k * N + r];
        if (!active) idx = -1;
        float s = (idx >= 0) ? 1.0f : 0.0f;
        const float4* xr  = (const float4*)(x + (long)(idx >= 0 ? idx : 0) * CI);
        const float4* Wk4 = (const float4*)(W + (long)k * CI * 32);
        CHUNK(0);
        if (CI == 32) {  // compile-time branch
            CHUNK(1); CHUNK(2); CHUNK(3);
            CHUNK(4); CHUNK(5); CHUNK(6); CHUNK(7);
        }
    }

    if (active) {
        float4* yr = (float4*)(y + (long)row * 32);
        yr[0] = a0; yr[1] = a1; yr[2] = a2; yr[3] = a3;
        yr[4] = a4; yr[5] = a5; yr[6] = a6; yr[7] = a7;
    }

    // BN stats (inactive rows hold zeros -> contribute nothing).
    bool lead = (threadIdx.x & 63) == 0;
#define RED4(av, base)                                          \
    red_one(av.x, &stats[base + 0], &stats[32 + base + 0], lead); \
    red_one(av.y, &stats[base + 1], &stats[32 + base + 1], lead); \
    red_one(av.z, &stats[base + 2], &stats[32 + base + 2], lead); \
    red_one(av.w, &stats[base + 3], &stats[32 + base + 3], lead);
    RED4(a0, 0)  RED4(a1, 4)  RED4(a2, 8)  RED4(a3, 12)
    RED4(a4, 16) RED4(a5, 20) RED4(a6, 24) RED4(a7, 28)
#undef RED4
}

// Elementwise BN (+optional residual) + ReLU. One thread per row-half
// (16 channels = 4 float4) so stats indexing stays compile-time constant.
__global__ __launch_bounds__(256) void bn_relu_kernel(
    const float* __restrict__ y, const float* __restrict__ stats,
    const float* __restrict__ gamma, const float* __restrict__ beta,
    const float* __restrict__ resid, float* __restrict__ out, int N)
{
    long i = (long)blockIdx.x * 256 + threadIdx.x;  // row-half index
    if (i >= (long)N * 2) return;
    int half = (int)(i & 1);
    int cb = half * 16;  // channel base: 0 or 16
    float inv_n = 1.0f / (float)N;

    const float4* yr = (const float4*)(y + i * 16);
    float4 v0 = yr[0], v1 = yr[1], v2 = yr[2], v3 = yr[3];

#define BNC(vv, j, cc)                                                   \
    {                                                                    \
        float mu = stats[cb + cc] * inv_n;                               \
        float var = stats[32 + cb + cc] * inv_n - mu * mu;               \
        float sc = rsqrtf(var + EPS) * gamma[cb + cc];                   \
        vv.j = (vv.j - mu) * sc + beta[cb + cc];                         \
    }
#define BN4(vv, base) BNC(vv, x, base + 0) BNC(vv, y, base + 1) \
                      BNC(vv, z, base + 2) BNC(vv, w, base + 3)
    BN4(v0, 0) BN4(v1, 4) BN4(v2, 8) BN4(v3, 12)
#undef BN4
#undef BNC

    if (resid) {
        const float4* rr = (const float4*)(resid + i * 16);
        v0 = add4(v0, rr[0]); v1 = add4(v1, rr[1]);
        v2 = add4(v2, rr[2]); v3 = add4(v3, rr[3]);
    }
    float4* outr = (float4*)(out + i * 16);
    outr[0] = relu4(v0); outr[1] = relu4(v1);
    outr[2] = relu4(v2); outr[3] = relu4(v3);
}

extern "C" void kernel_launch(void* const* d_in, const int* in_sizes, int n_in,
                              void* d_out, int out_size, void* d_ws, size_t ws_size,
                              hipStream_t stream)
{
    const float* vf   = (const float*)d_in[0];
    const float* Ws1  = (const float*)d_in[1];
    const float* Ws2  = (const float*)d_in[2];
    const float* Wd   = (const float*)d_in[3];
    const float* Wr1a = (const float*)d_in[4];
    const float* Wr1b = (const float*)d_in[5];
    const float* Wr2a = (const float*)d_in[6];
    const float* Wr2b = (const float*)d_in[7];
    const float* gam  = (const float*)d_in[8];
    const float* bet  = (const float*)d_in[9];
    const int* nbr0   = (const int*)d_in[10];
    const int* down1  = (const int*)d_in[11];
    const int* nbr1   = (const int*)d_in[12];

    int N0 = in_sizes[0] / 4;
    int N1 = in_sizes[11] / 8;

    float* bufA  = (float*)d_ws;                 // N0*32 floats
    float* bufB  = bufA + (size_t)N0 * 32;       // N0*32 floats
    float* stats = bufB + (size_t)N0 * 32;       // 7*64 floats
    float* out   = (float*)d_out;                // N1*32 floats (also raw-conv scratch)

    hipMemsetAsync(stats, 0, 7 * 64 * sizeof(float), stream);

    auto cgrid = [](int n) { return dim3((unsigned)((n + 255) / 256)); };
    auto bgrid = [](long n) { return dim3((unsigned)((n * 2 + 255) / 256)); };

    // stem1: vf -> bufA
    conv_kernel<4, 27><<<cgrid(N0), 256, 0, stream>>>(vf, nbr0, Ws1, bufA, stats + 0 * 64, N0);
    bn_relu_kernel<<<bgrid(N0), 256, 0, stream>>>(bufA, stats + 0 * 64, gam + 0, bet + 0, nullptr, bufA, N0);
    // stem2: bufA -> bufB
    conv_kernel<32, 27><<<cgrid(N0), 256, 0, stream>>>(bufA, nbr0, Ws2, bufB, stats + 1 * 64, N0);
    bn_relu_kernel<<<bgrid(N0), 256, 0, stream>>>(bufB, stats + 1 * 64, gam + 32, bet + 32, nullptr, bufB, N0);
    // down: bufB -> bufA (x1)
    conv_kernel<32, 8><<<cgrid(N1), 256, 0, stream>>>(bufB, down1, Wd, bufA, stats + 2 * 64, N1);
    bn_relu_kernel<<<bgrid(N1), 256, 0, stream>>>(bufA, stats + 2 * 64, gam + 64, bet + 64, nullptr, bufA, N1);
    // r1a: bufA -> bufB (h)
    conv_kernel<32, 27><<<cgrid(N1), 256, 0, stream>>>(bufA, nbr1, Wr1a, bufB, stats + 3 * 64, N1);
    bn_relu_kernel<<<bgrid(N1), 256, 0, stream>>>(bufB, stats + 3 * 64, gam + 96, bet + 96, nullptr, bufB, N1);
    // r1b: bufB -> d_out (raw), then x1' = relu(bn(d_out) + bufA) -> bufA
    conv_kernel<32, 27><<<cgrid(N1), 256, 0, stream>>>(bufB, nbr1, Wr1b, out, stats + 4 * 64, N1);
    bn_relu_kernel<<<bgrid(N1), 256, 0, stream>>>(out, stats + 4 * 64, gam + 128, bet + 128, bufA, bufA, N1);
    // r2a: bufA -> bufB (h)
    conv_kernel<32, 27><<<cgrid(N1), 256, 0, stream>>>(bufA, nbr1, Wr2a, bufB, stats + 5 * 64, N1);
    bn_relu_kernel<<<bgrid(N1), 256, 0, stream>>>(bufB, stats + 5 * 64, gam + 160, bet + 160, nullptr, bufB, N1);
    // r2b: bufB -> d_out (raw), then out = relu(bn(d_out) + bufA) -> d_out
    conv_kernel<32, 27><<<cgrid(N1), 256, 0, stream>>>(bufB, nbr1, Wr2b, out, stats + 6 * 64, N1);
    bn_relu_kernel<<<bgrid(N1), 256, 0, stream>>>(out, stats + 6 * 64, gam + 192, bet + 192, bufA, out, N1);
}

// Round 5
// 2893.231 us; speedup vs baseline: 5.5971x; 5.3620x over previous
//
#include <hip/hip_runtime.h>

#define EPS 1e-5f

typedef __attribute__((ext_vector_type(8))) short short8;     // 8 bf16 (4 VGPR) MFMA frag
typedef __attribute__((ext_vector_type(4))) float floatx4;    // MFMA C/D frag
typedef __attribute__((ext_vector_type(8))) unsigned short ushort8;

// bf16 <-> f32 (RTNE)
__device__ __forceinline__ unsigned short f2bf(float f) {
    union { float f; unsigned u; } x; x.f = f;
    unsigned r = x.u + 0x7fffu + ((x.u >> 16) & 1u);
    return (unsigned short)(r >> 16);
}
__device__ __forceinline__ float bf2f(unsigned short b) {
    union { unsigned u; float f; } x; x.u = ((unsigned)b) << 16;
    return x.f;
}

// ---------------------------------------------------------------------------
// Weight pack: W[k][ci][co] fp32 -> B-fragment order for mfma_f32_16x16x32_bf16.
// Out element (k, h, lane, j) = bf16(W[k][ci = (lane>>4)*8 + j][co = h*16 + (lane&15)])
// stored at out[((k*2+h)*64 + lane)*8 + j]. One thread packs 8 (one 16B chunk).
__global__ __launch_bounds__(256) void pack_w_kernel(
    const float* __restrict__ W, unsigned short* __restrict__ out, int K)
{
    int t = blockIdx.x * 256 + threadIdx.x;
    if (t >= K * 128) return;
    int lane = t & 63;
    int h = (t >> 6) & 1;
    int k = t >> 7;
    int m = lane & 15, q = lane >> 4;
    ushort8 v;
#pragma unroll
    for (int j = 0; j < 8; ++j)
        v[j] = f2bf(W[((size_t)k * 32 + q * 8 + j) * 32 + h * 16 + m]);
    *(ushort8*)(out + (size_t)t * 8) = v;
}

// ---------------------------------------------------------------------------
// MFMA sparse conv: per tap k, C[rows,32] += gather(A)[rows,32] @ Wk[32,32].
// 256 thr = 4 waves; wave handles 32 rows (2 tiles of 16). Every lane loads
// DISTINCT 16B of A and B (no wave-uniform redundancy -- the round<=4 killer).
// A layout (guide-verified): lane = q*16+m holds A[m][k=q*8+j].
// Fused BN stats from fp32 accs (pre-bf16-rounding).
template <int K>
__global__ __launch_bounds__(256) void conv_mfma_kernel(
    const unsigned short* __restrict__ x,   // [Nx][32] bf16 activations
    const int* __restrict__ nbr,            // [K][N]
    const unsigned short* __restrict__ Wp,  // packed [K][2][64][8] bf16
    unsigned short* __restrict__ y,         // [N][32] bf16 raw conv out
    float* __restrict__ stats, int N)
{
    const int lane = threadIdx.x & 63;
    const int wave = threadIdx.x >> 6;
    const int m = lane & 15, q = lane >> 4;
    const int rowbase = blockIdx.x * 128 + wave * 32;
    const int row0 = rowbase + m;
    const int row1 = rowbase + 16 + m;

    floatx4 acc00 = {0.f, 0.f, 0.f, 0.f};
    floatx4 acc01 = acc00, acc10 = acc00, acc11 = acc00;

    for (int k = 0; k < K; ++k) {
        int i0 = (row0 < N) ? nbr[(size_t)k * N + row0] : -1;
        int i1 = (row1 < N) ? nbr[(size_t)k * N + row1] : -1;
        short8 a0 = {}, a1 = {};
        if (i0 >= 0) a0 = *(const short8*)(x + (size_t)i0 * 32 + q * 8);
        if (i1 >= 0) a1 = *(const short8*)(x + (size_t)i1 * 32 + q * 8);
        const short8* wk = (const short8*)(Wp + (size_t)k * 2 * 64 * 8);
        short8 b0 = wk[lane];
        short8 b1 = wk[64 + lane];
        acc00 = __builtin_amdgcn_mfma_f32_16x16x32_bf16(a0, b0, acc00, 0, 0, 0);
        acc01 = __builtin_amdgcn_mfma_f32_16x16x32_bf16(a0, b1, acc01, 0, 0, 0);
        acc10 = __builtin_amdgcn_mfma_f32_16x16x32_bf16(a1, b0, acc10, 0, 0, 0);
        acc11 = __builtin_amdgcn_mfma_f32_16x16x32_bf16(a1, b1, acc11, 0, 0, 0);
    }

    // C/D layout (guide-verified, m89): col = lane&15, row(within tile) = q*4 + r.
#pragma unroll
    for (int r = 0; r < 4; ++r) {
        int ra = rowbase + q * 4 + r;        // tile 0
        int rb = ra + 16;                    // tile 1
        if (ra < N) {
            y[(size_t)ra * 32 + m]      = f2bf(acc00[r]);
            y[(size_t)ra * 32 + 16 + m] = f2bf(acc01[r]);
        }
        if (rb < N) {
            y[(size_t)rb * 32 + m]      = f2bf(acc10[r]);
            y[(size_t)rb * 32 + 16 + m] = f2bf(acc11[r]);
        }
    }

    // BN stats: per lane, sum over its 8 rows (2 tiles x 4 regs) for channel
    // co = h*16 + m; lanes l, l+16, l+32, l+48 hold the remaining rows.
    float s0 = 0.f, q0 = 0.f, s1 = 0.f, q1 = 0.f;
#pragma unroll
    for (int r = 0; r < 4; ++r) {
        s0 += acc00[r] + acc10[r];
        q0 += acc00[r] * acc00[r] + acc10[r] * acc10[r];
        s1 += acc01[r] + acc11[r];
        q1 += acc01[r] * acc01[r] + acc11[r] * acc11[r];
    }
    s0 += __shfl_down(s0, 32); s0 += __shfl_down(s0, 16);
    q0 += __shfl_down(q0, 32); q0 += __shfl_down(q0, 16);
    s1 += __shfl_down(s1, 32); s1 += __shfl_down(s1, 16);
    q1 += __shfl_down(q1, 32); q1 += __shfl_down(q1, 16);
    if (lane < 16) {
        atomicAdd(&stats[m],      s0);
        atomicAdd(&stats[32 + m], q0);
        atomicAdd(&stats[16 + m],      s1);
        atomicAdd(&stats[32 + 16 + m], q1);
    }
}

// ---------------------------------------------------------------------------
// stem1: CI=4 fp32 input (vf), VALU kernel (W traffic is 1/8 of CI=32 case).
// One thread per row; 32 accs as 8 named float4s. Outputs bf16 + stats.
__device__ __forceinline__ float4 fma4(float s, float4 w, float4 a) {
    a.x = fmaf(s, w.x, a.x); a.y = fmaf(s, w.y, a.y);
    a.z = fmaf(s, w.z, a.z); a.w = fmaf(s, w.w, a.w);
    return a;
}
__device__ __forceinline__ void red_one(float v, float* s_dst, float* q_dst, bool lead) {
    float s = v, q = v * v;
#pragma unroll
    for (int off = 32; off >= 1; off >>= 1) {
        s += __shfl_down(s, off);
        q += __shfl_down(q, off);
    }
    if (lead) { atomicAdd(s_dst, s); atomicAdd(q_dst, q); }
}

__global__ __launch_bounds__(256, 4) void conv_stem1_kernel(
    const float* __restrict__ x, const int* __restrict__ nbr,
    const float* __restrict__ W, unsigned short* __restrict__ y,
    float* __restrict__ stats, int N)
{
    int row = blockIdx.x * 256 + threadIdx.x;
    bool active = row < N;
    int r = active ? row : 0;

    float4 a0 = make_float4(0.f, 0.f, 0.f, 0.f), a1 = a0, a2 = a0, a3 = a0,
           a4 = a0, a5 = a0, a6 = a0, a7 = a0;

#pragma unroll 1
    for (int k = 0; k < 27; ++k) {
        int idx = nbr[(size_t)k * N + r];
        if (!active) idx = -1;
        float s = (idx >= 0) ? 1.0f : 0.0f;
        float4 xv = *(const float4*)(x + (size_t)(idx >= 0 ? idx : 0) * 4);
        xv.x *= s; xv.y *= s; xv.z *= s; xv.w *= s;
        const float4* Wk = (const float4*)(W + (size_t)k * 4 * 32);
#define STEP(xs, ci)                      \
        a0 = fma4(xs, Wk[(ci)*8 + 0], a0); a1 = fma4(xs, Wk[(ci)*8 + 1], a1); \
        a2 = fma4(xs, Wk[(ci)*8 + 2], a2); a3 = fma4(xs, Wk[(ci)*8 + 3], a3); \
        a4 = fma4(xs, Wk[(ci)*8 + 4], a4); a5 = fma4(xs, Wk[(ci)*8 + 5], a5); \
        a6 = fma4(xs, Wk[(ci)*8 + 6], a6); a7 = fma4(xs, Wk[(ci)*8 + 7], a7);
        STEP(xv.x, 0) STEP(xv.y, 1) STEP(xv.z, 2) STEP(xv.w, 3)
#undef STEP
    }

    if (active) {
        unsigned short* yr = y + (size_t)row * 32;
        ushort8 o;
#define PK(av, bv, base)                                              \
        o[0] = f2bf(av.x); o[1] = f2bf(av.y); o[2] = f2bf(av.z); o[3] = f2bf(av.w); \
        o[4] = f2bf(bv.x); o[5] = f2bf(bv.y); o[6] = f2bf(bv.z); o[7] = f2bf(bv.w); \
        *(ushort8*)(yr + base) = o;
        PK(a0, a1, 0) PK(a2, a3, 8) PK(a4, a5, 16) PK(a6, a7, 24)
#undef PK
    }

    bool lead = (threadIdx.x & 63) == 0;
#define RED4(av, base)                                              \
    red_one(av.x, &stats[base + 0], &stats[32 + base + 0], lead);   \
    red_one(av.y, &stats[base + 1], &stats[32 + base + 1], lead);   \
    red_one(av.z, &stats[base + 2], &stats[32 + base + 2], lead);   \
    red_one(av.w, &stats[base + 3], &stats[32 + base + 3], lead);
    RED4(a0, 0)  RED4(a1, 4)  RED4(a2, 8)  RED4(a3, 12)
    RED4(a4, 16) RED4(a5, 20) RED4(a6, 24) RED4(a7, 28)
#undef RED4
}

// ---------------------------------------------------------------------------
// BN (+optional bf16 residual) + ReLU. Reads bf16 y, writes bf16 activation
// or fp32 final output. One thread per row (32 channels, unrolled).
template <bool OUT_F32, bool HAS_RES>
__global__ __launch_bounds__(256) void bn_relu_kernel(
    const unsigned short* __restrict__ y, const float* __restrict__ stats,
    const float* __restrict__ gamma, const float* __restrict__ beta,
    const unsigned short* __restrict__ resid, void* __restrict__ outp, int N)
{
    int t = blockIdx.x * 256 + threadIdx.x;
    if (t >= N) return;
    float inv_n = 1.0f / (float)N;
    const ushort8* yr = (const ushort8*)(y + (size_t)t * 32);

#pragma unroll
    for (int c = 0; c < 4; ++c) {
        ushort8 v = yr[c];
        ushort8 rv = {};
        if (HAS_RES) rv = ((const ushort8*)(resid + (size_t)t * 32))[c];
        float f0, f1, f2, f3, f4, f5, f6, f7;
#define BNJ(fj, j)                                                        \
        {                                                                 \
            int co = c * 8 + (j);                                         \
            float mu = stats[co] * inv_n;                                 \
            float var = stats[32 + co] * inv_n - mu * mu;                 \
            float sc = rsqrtf(var + EPS) * gamma[co];                     \
            fj = (bf2f(v[j]) - mu) * sc + beta[co];                       \
            if (HAS_RES) fj += bf2f(rv[j]);                               \
            fj = fmaxf(fj, 0.0f);                                         \
        }
        BNJ(f0, 0) BNJ(f1, 1) BNJ(f2, 2) BNJ(f3, 3)
        BNJ(f4, 4) BNJ(f5, 5) BNJ(f6, 6) BNJ(f7, 7)
#undef BNJ
        if (OUT_F32) {
            float* ob = (float*)outp + (size_t)t * 32 + c * 8;
            floatx4 u0 = {f0, f1, f2, f3}, u1 = {f4, f5, f6, f7};
            *(floatx4*)(ob) = u0;
            *(floatx4*)(ob + 4) = u1;
        } else {
            ushort8 o;
            o[0] = f2bf(f0); o[1] = f2bf(f1); o[2] = f2bf(f2); o[3] = f2bf(f3);
            o[4] = f2bf(f4); o[5] = f2bf(f5); o[6] = f2bf(f6); o[7] = f2bf(f7);
            ((ushort8*)((unsigned short*)outp + (size_t)t * 32))[c] = o;
        }
    }
}

// ---------------------------------------------------------------------------
extern "C" void kernel_launch(void* const* d_in, const int* in_sizes, int n_in,
                              void* d_out, int out_size, void* d_ws, size_t ws_size,
                              hipStream_t stream)
{
    const float* vf   = (const float*)d_in[0];
    const float* Ws1  = (const float*)d_in[1];
    const float* Ws2  = (const float*)d_in[2];
    const float* Wd   = (const float*)d_in[3];
    const float* Wr1a = (const float*)d_in[4];
    const float* Wr1b = (const float*)d_in[5];
    const float* Wr2a = (const float*)d_in[6];
    const float* Wr2b = (const float*)d_in[7];
    const float* gam  = (const float*)d_in[8];
    const float* bet  = (const float*)d_in[9];
    const int* nbr0   = (const int*)d_in[10];
    const int* down1  = (const int*)d_in[11];
    const int* nbr1   = (const int*)d_in[12];

    int N0 = in_sizes[0] / 4;
    int N1 = in_sizes[11] / 8;

    // ws layout (bf16 buffers as unsigned short)
    unsigned short* yraw = (unsigned short*)d_ws;            // N0*32
    unsigned short* actA = yraw + (size_t)N0 * 32;           // N0*32
    unsigned short* actB = actA + (size_t)N0 * 32;           // N0*32
    unsigned short* wp   = actB + (size_t)N0 * 32;           // packed weights
    const size_t o_s2  = 0;
    const size_t o_dn  = o_s2 + 27 * 1024;
    const size_t o_r1a = o_dn + 8 * 1024;
    const size_t o_r1b = o_r1a + 27 * 1024;
    const size_t o_r2a = o_r1b + 27 * 1024;
    const size_t o_r2b = o_r2a + 27 * 1024;
    float* stats = (float*)(wp + o_r2b + 27 * 1024 + 64);    // 7*64 fp32

    hipMemsetAsync(stats, 0, 7 * 64 * sizeof(float), stream);

    // Pack weights into MFMA B-fragment order (bf16).
    pack_w_kernel<<<(27 * 128 + 255) / 256, 256, 0, stream>>>(Ws2,  wp + o_s2,  27);
    pack_w_kernel<<<(8  * 128 + 255) / 256, 256, 0, stream>>>(Wd,   wp + o_dn,  8);
    pack_w_kernel<<<(27 * 128 + 255) / 256, 256, 0, stream>>>(Wr1a, wp + o_r1a, 27);
    pack_w_kernel<<<(27 * 128 + 255) / 256, 256, 0, stream>>>(Wr1b, wp + o_r1b, 27);
    pack_w_kernel<<<(27 * 128 + 255) / 256, 256, 0, stream>>>(Wr2a, wp + o_r2a, 27);
    pack_w_kernel<<<(27 * 128 + 255) / 256, 256, 0, stream>>>(Wr2b, wp + o_r2b, 27);

    auto g1 = [](int n) { return dim3((unsigned)((n + 255) / 256)); };   // thread/row
    auto gm = [](int n) { return dim3((unsigned)((n + 127) / 128)); };   // mfma: 128 rows/block

    // stem1: vf -> yraw; act -> actA
    conv_stem1_kernel<<<g1(N0), 256, 0, stream>>>(vf, nbr0, Ws1, yraw, stats + 0 * 64, N0);
    bn_relu_kernel<false, false><<<g1(N0), 256, 0, stream>>>(yraw, stats + 0 * 64, gam + 0, bet + 0, nullptr, actA, N0);
    // stem2: actA -> yraw; act -> actB
    conv_mfma_kernel<27><<<gm(N0), 256, 0, stream>>>(actA, nbr0, wp + o_s2, yraw, stats + 1 * 64, N0);
    bn_relu_kernel<false, false><<<g1(N0), 256, 0, stream>>>(yraw, stats + 1 * 64, gam + 32, bet + 32, nullptr, actB, N0);
    // down: actB (N0 rows) -> yraw (N1); x1 -> actA
    conv_mfma_kernel<8><<<gm(N1), 256, 0, stream>>>(actB, down1, wp + o_dn, yraw, stats + 2 * 64, N1);
    bn_relu_kernel<false, false><<<g1(N1), 256, 0, stream>>>(yraw, stats + 2 * 64, gam + 64, bet + 64, nullptr, actA, N1);
    // r1a: actA -> yraw; h -> actB
    conv_mfma_kernel<27><<<gm(N1), 256, 0, stream>>>(actA, nbr1, wp + o_r1a, yraw, stats + 3 * 64, N1);
    bn_relu_kernel<false, false><<<g1(N1), 256, 0, stream>>>(yraw, stats + 3 * 64, gam + 96, bet + 96, nullptr, actB, N1);
    // r1b: actB -> yraw; x1' = relu(bn(yraw) + actA) -> actB
    conv_mfma_kernel<27><<<gm(N1), 256, 0, stream>>>(actB, nbr1, wp + o_r1b, yraw, stats + 4 * 64, N1);
    bn_relu_kernel<false, true><<<g1(N1), 256, 0, stream>>>(yraw, stats + 4 * 64, gam + 128, bet + 128, actA, actB, N1);
    // r2a: actB -> yraw; h2 -> actA
    conv_mfma_kernel<27><<<gm(N1), 256, 0, stream>>>(actB, nbr1, wp + o_r2a, yraw, stats + 5 * 64, N1);
    bn_relu_kernel<false, false><<<g1(N1), 256, 0, stream>>>(yraw, stats + 5 * 64, gam + 160, bet + 160, nullptr, actA, N1);
    // r2b: actA -> yraw; out = relu(bn(yraw) + actB) -> d_out (fp32)
    conv_mfma_kernel<27><<<gm(N1), 256, 0, stream>>>(actA, nbr1, wp + o_r2b, yraw, stats + 6 * 64, N1);
    bn_relu_kernel<true, true><<<g1(N1), 256, 0, stream>>>(yraw, stats + 6 * 64, gam + 192, bet + 192, actB, d_out, N1);
}

// Round 6
// 1690.147 us; speedup vs baseline: 9.5813x; 1.7118x over previous
//
#include <hip/hip_runtime.h>

#define EPS 1e-5f

typedef __attribute__((ext_vector_type(8))) short short8;            // 8 bf16 MFMA frag
typedef __attribute__((ext_vector_type(4))) float floatx4;           // MFMA C/D frag
typedef __attribute__((ext_vector_type(8))) unsigned short ushort8;
typedef __attribute__((ext_vector_type(4))) unsigned short ushortv4;

// bf16 <-> f32 (RTNE)
__device__ __forceinline__ unsigned short f2bf(float f) {
    union { float f; unsigned u; } x; x.f = f;
    unsigned r = x.u + 0x7fffu + ((x.u >> 16) & 1u);
    return (unsigned short)(r >> 16);
}
__device__ __forceinline__ float bf2f(unsigned short b) {
    union { unsigned u; float f; } x; x.u = ((unsigned)b) << 16;
    return x.f;
}

// ---------------------------------------------------------------------------
// vf fp32 [N][4] -> bf16 [N][4]
__global__ __launch_bounds__(256) void cvt_kernel(
    const float* __restrict__ x, unsigned short* __restrict__ o, int N)
{
    int t = blockIdx.x * 256 + threadIdx.x;
    if (t >= N) return;
    float4 v = *(const float4*)(x + (size_t)t * 4);
    ushortv4 r = {f2bf(v.x), f2bf(v.y), f2bf(v.z), f2bf(v.w)};
    *(ushortv4*)(o + (size_t)t * 4) = r;
}

// ---------------------------------------------------------------------------
// Weight pack (CI=32 convs): W[k][ci][co] fp32 -> B-frag order, 16x16x32 bf16.
// out[((k*2+h)*64 + lane)*8 + j] = bf16(W[k][(lane>>4)*8 + j][h*16 + (lane&15)])
__global__ __launch_bounds__(256) void pack_w_kernel(
    const float* __restrict__ W, unsigned short* __restrict__ out, int K)
{
    int t = blockIdx.x * 256 + threadIdx.x;
    if (t >= K * 128) return;
    int lane = t & 63;
    int h = (t >> 6) & 1;
    int k = t >> 7;
    int m = lane & 15, q = lane >> 4;
    ushort8 v;
#pragma unroll
    for (int j = 0; j < 8; ++j)
        v[j] = f2bf(W[((size_t)k * 32 + q * 8 + j) * 32 + h * 16 + m]);
    *(ushort8*)(out + (size_t)t * 8) = v;
}

// Weight pack for stem1: W[27][4][32], kdim = t*4+ci folded to 4 chunks of K=32,
// taps 27..31 zero-padded. out[((c*2+h)*64 + lane)*8 + j].
__global__ __launch_bounds__(256) void pack_w1_kernel(
    const float* __restrict__ W, unsigned short* __restrict__ out)
{
    int t = blockIdx.x * 256 + threadIdx.x;
    if (t >= 512) return;  // 4 chunks * 2 halves * 64 lanes
    int lane = t & 63;
    int h = (t >> 6) & 1;
    int c = t >> 7;
    int m = lane & 15, q = lane >> 4;
    ushort8 v;
#pragma unroll
    for (int j = 0; j < 8; ++j) {
        int kdim = c * 32 + q * 8 + j;
        int tap = kdim >> 2, ci = kdim & 3;
        v[j] = (tap < 27) ? f2bf(W[((size_t)tap * 4 + ci) * 32 + h * 16 + m]) : 0;
    }
    *(ushort8*)(out + (size_t)t * 8) = v;
}

// ---------------------------------------------------------------------------
// Shared epilogue: C-layout stores (bf16) + BN partial sums -> LDS -> part[block].
// acc layout (16x16x32, guide-verified): col = lane&15, row-in-tile = (lane>>4)*4 + r.
__device__ __forceinline__ void conv_epilogue(
    floatx4 acc00, floatx4 acc01, floatx4 acc10, floatx4 acc11,
    unsigned short* __restrict__ y, float* __restrict__ part,
    int rowbase, int N, float* sm)
{
    const int lane = threadIdx.x & 63;
    const int m = lane & 15, q = lane >> 4;

    if (threadIdx.x < 64) sm[threadIdx.x] = 0.f;
    __syncthreads();

#pragma unroll
    for (int r = 0; r < 4; ++r) {
        int ra = rowbase + q * 4 + r;
        int rb = ra + 16;
        if (ra < N) {
            y[(size_t)ra * 32 + m]      = f2bf(acc00[r]);
            y[(size_t)ra * 32 + 16 + m] = f2bf(acc01[r]);
        }
        if (rb < N) {
            y[(size_t)rb * 32 + m]      = f2bf(acc10[r]);
            y[(size_t)rb * 32 + 16 + m] = f2bf(acc11[r]);
        }
    }

    float s0 = 0.f, q0 = 0.f, s1 = 0.f, q1 = 0.f;
#pragma unroll
    for (int r = 0; r < 4; ++r) {
        s0 += acc00[r] + acc10[r];
        q0 += acc00[r] * acc00[r] + acc10[r] * acc10[r];
        s1 += acc01[r] + acc11[r];
        q1 += acc01[r] * acc01[r] + acc11[r] * acc11[r];
    }
    s0 += __shfl_down(s0, 32); s0 += __shfl_down(s0, 16);
    q0 += __shfl_down(q0, 32); q0 += __shfl_down(q0, 16);
    s1 += __shfl_down(s1, 32); s1 += __shfl_down(s1, 16);
    q1 += __shfl_down(q1, 32); q1 += __shfl_down(q1, 16);
    if (lane < 16) {
        atomicAdd(&sm[m],      s0);
        atomicAdd(&sm[32 + m], q0);
        atomicAdd(&sm[16 + m],      s1);
        atomicAdd(&sm[48 + m], q1);
    }
    __syncthreads();
    if (threadIdx.x < 64)
        part[(size_t)blockIdx.x * 64 + threadIdx.x] = sm[threadIdx.x];
}

// ---------------------------------------------------------------------------
// MFMA sparse conv (CI=32): per tap, C[rows,32] += gather(A)[rows,32] @ Wk[32,32].
// 256 thr = 4 waves; wave covers 32 rows (2 tiles) x 32 co (2 halves) = 4 accs.
template <int K>
__global__ __launch_bounds__(256) void conv_mfma_kernel(
    const unsigned short* __restrict__ x,   // [Nx][32] bf16
    const int* __restrict__ nbr,            // [K][N]
    const unsigned short* __restrict__ Wp,  // packed [K][2][64][8]
    unsigned short* __restrict__ y,         // [N][32] bf16
    float* __restrict__ part, int N)
{
    __shared__ float sm[64];
    const int lane = threadIdx.x & 63;
    const int wave = threadIdx.x >> 6;
    const int m = lane & 15, q = lane >> 4;
    const int rowbase = blockIdx.x * 128 + wave * 32;
    const int row0 = rowbase + m;
    const int row1 = rowbase + 16 + m;

    floatx4 acc00 = {0.f, 0.f, 0.f, 0.f};
    floatx4 acc01 = acc00, acc10 = acc00, acc11 = acc00;

    for (int k = 0; k < K; ++k) {
        int i0 = (row0 < N) ? nbr[(size_t)k * N + row0] : -1;
        int i1 = (row1 < N) ? nbr[(size_t)k * N + row1] : -1;
        short8 a0 = {}, a1 = {};
        if (i0 >= 0) a0 = *(const short8*)(x + (size_t)i0 * 32 + q * 8);
        if (i1 >= 0) a1 = *(const short8*)(x + (size_t)i1 * 32 + q * 8);
        const short8* wk = (const short8*)(Wp + (size_t)k * 2 * 64 * 8);
        short8 b0 = wk[lane];
        short8 b1 = wk[64 + lane];
        acc00 = __builtin_amdgcn_mfma_f32_16x16x32_bf16(a0, b0, acc00, 0, 0, 0);
        acc01 = __builtin_amdgcn_mfma_f32_16x16x32_bf16(a0, b1, acc01, 0, 0, 0);
        acc10 = __builtin_amdgcn_mfma_f32_16x16x32_bf16(a1, b0, acc10, 0, 0, 0);
        acc11 = __builtin_amdgcn_mfma_f32_16x16x32_bf16(a1, b1, acc11, 0, 0, 0);
    }

    conv_epilogue(acc00, acc01, acc10, acc11, y, part, rowbase, N, sm);
}

// ---------------------------------------------------------------------------
// stem1 as MFMA: CI=4, 27 taps folded into kdim = tap*4+ci, 4 chunks of K=32.
// Lane (q,m) in chunk c gathers taps t0=c*8+q*2 and t0+1 (4 bf16 = 8B each).
__global__ __launch_bounds__(256) void conv_stem1_mfma(
    const unsigned short* __restrict__ xb,  // [N][4] bf16
    const int* __restrict__ nbr,            // [27][N]
    const unsigned short* __restrict__ Wp,  // packed [4][2][64][8]
    unsigned short* __restrict__ y,         // [N][32] bf16
    float* __restrict__ part, int N)
{
    __shared__ float sm[64];
    const int lane = threadIdx.x & 63;
    const int wave = threadIdx.x >> 6;
    const int m = lane & 15, q = lane >> 4;
    const int rowbase = blockIdx.x * 128 + wave * 32;
    const int row0 = rowbase + m;
    const int row1 = rowbase + 16 + m;

    floatx4 acc00 = {0.f, 0.f, 0.f, 0.f};
    floatx4 acc01 = acc00, acc10 = acc00, acc11 = acc00;

#pragma unroll
    for (int c = 0; c < 4; ++c) {
        const int t0 = c * 8 + q * 2, t1 = t0 + 1;
        short8 a0 = {}, a1 = {};
        {
            int ia = (t0 < 27 && row0 < N) ? nbr[(size_t)t0 * N + row0] : -1;
            int ib = (t1 < 27 && row0 < N) ? nbr[(size_t)t1 * N + row0] : -1;
            ushortv4 ga = {}, gb = {};
            if (ia >= 0) ga = *(const ushortv4*)(xb + (size_t)ia * 4);
            if (ib >= 0) gb = *(const ushortv4*)(xb + (size_t)ib * 4);
            a0[0] = (short)ga[0]; a0[1] = (short)ga[1];
            a0[2] = (short)ga[2]; a0[3] = (short)ga[3];
            a0[4] = (short)gb[0]; a0[5] = (short)gb[1];
            a0[6] = (short)gb[2]; a0[7] = (short)gb[3];
        }
        {
            int ia = (t0 < 27 && row1 < N) ? nbr[(size_t)t0 * N + row1] : -1;
            int ib = (t1 < 27 && row1 < N) ? nbr[(size_t)t1 * N + row1] : -1;
            ushortv4 ga = {}, gb = {};
            if (ia >= 0) ga = *(const ushortv4*)(xb + (size_t)ia * 4);
            if (ib >= 0) gb = *(const ushortv4*)(xb + (size_t)ib * 4);
            a1[0] = (short)ga[0]; a1[1] = (short)ga[1];
            a1[2] = (short)ga[2]; a1[3] = (short)ga[3];
            a1[4] = (short)gb[0]; a1[5] = (short)gb[1];
            a1[6] = (short)gb[2]; a1[7] = (short)gb[3];
        }
        const short8* wk = (const short8*)Wp;
        short8 b0 = wk[(c * 2 + 0) * 64 + lane];
        short8 b1 = wk[(c * 2 + 1) * 64 + lane];
        acc00 = __builtin_amdgcn_mfma_f32_16x16x32_bf16(a0, b0, acc00, 0, 0, 0);
        acc01 = __builtin_amdgcn_mfma_f32_16x16x32_bf16(a0, b1, acc01, 0, 0, 0);
        acc10 = __builtin_amdgcn_mfma_f32_16x16x32_bf16(a1, b0, acc10, 0, 0, 0);
        acc11 = __builtin_amdgcn_mfma_f32_16x16x32_bf16(a1, b1, acc11, 0, 0, 0);
    }

    conv_epilogue(acc00, acc01, acc10, acc11, y, part, rowbase, N, sm);
}

// ---------------------------------------------------------------------------
// Deterministic stat reduction: part[nb][64] -> stats[64]. 1 block, 256 thr.
__global__ __launch_bounds__(256) void reduce_stats_kernel(
    const float* __restrict__ part, float* __restrict__ stats, int nb)
{
    __shared__ float sm[256];
    int t = threadIdx.x;
    int c = t & 63, g = t >> 6;
    float s = 0.f;
    for (int b = g; b < nb; b += 4) s += part[(size_t)b * 64 + c];
    sm[t] = s;
    __syncthreads();
    if (t < 64) stats[t] = sm[t] + sm[64 + t] + sm[128 + t] + sm[192 + t];
}

// ---------------------------------------------------------------------------
// BN (+optional bf16 residual) + ReLU. bf16 in; bf16 or fp32 out.
template <bool OUT_F32, bool HAS_RES>
__global__ __launch_bounds__(256) void bn_relu_kernel(
    const unsigned short* __restrict__ y, const float* __restrict__ stats,
    const float* __restrict__ gamma, const float* __restrict__ beta,
    const unsigned short* __restrict__ resid, void* __restrict__ outp, int N)
{
    int t = blockIdx.x * 256 + threadIdx.x;
    if (t >= N) return;
    float inv_n = 1.0f / (float)N;
    const ushort8* yr = (const ushort8*)(y + (size_t)t * 32);

#pragma unroll
    for (int c = 0; c < 4; ++c) {
        ushort8 v = yr[c];
        ushort8 rv = {};
        if (HAS_RES) rv = ((const ushort8*)(resid + (size_t)t * 32))[c];
        float f0, f1, f2, f3, f4, f5, f6, f7;
#define BNJ(fj, j)                                                        \
        {                                                                 \
            int co = c * 8 + (j);                                         \
            float mu = stats[co] * inv_n;                                 \
            float var = stats[32 + co] * inv_n - mu * mu;                 \
            float sc = rsqrtf(var + EPS) * gamma[co];                     \
            fj = (bf2f(v[j]) - mu) * sc + beta[co];                       \
            if (HAS_RES) fj += bf2f(rv[j]);                               \
            fj = fmaxf(fj, 0.0f);                                         \
        }
        BNJ(f0, 0) BNJ(f1, 1) BNJ(f2, 2) BNJ(f3, 3)
        BNJ(f4, 4) BNJ(f5, 5) BNJ(f6, 6) BNJ(f7, 7)
#undef BNJ
        if (OUT_F32) {
            float* ob = (float*)outp + (size_t)t * 32 + c * 8;
            floatx4 u0 = {f0, f1, f2, f3}, u1 = {f4, f5, f6, f7};
            *(floatx4*)(ob) = u0;
            *(floatx4*)(ob + 4) = u1;
        } else {
            ushort8 o;
            o[0] = f2bf(f0); o[1] = f2bf(f1); o[2] = f2bf(f2); o[3] = f2bf(f3);
            o[4] = f2bf(f4); o[5] = f2bf(f5); o[6] = f2bf(f6); o[7] = f2bf(f7);
            ((ushort8*)((unsigned short*)outp + (size_t)t * 32))[c] = o;
        }
    }
}

// ---------------------------------------------------------------------------
extern "C" void kernel_launch(void* const* d_in, const int* in_sizes, int n_in,
                              void* d_out, int out_size, void* d_ws, size_t ws_size,
                              hipStream_t stream)
{
    const float* vf   = (const float*)d_in[0];
    const float* Ws1  = (const float*)d_in[1];
    const float* Ws2  = (const float*)d_in[2];
    const float* Wd   = (const float*)d_in[3];
    const float* Wr1a = (const float*)d_in[4];
    const float* Wr1b = (const float*)d_in[5];
    const float* Wr2a = (const float*)d_in[6];
    const float* Wr2b = (const float*)d_in[7];
    const float* gam  = (const float*)d_in[8];
    const float* bet  = (const float*)d_in[9];
    const int* nbr0   = (const int*)d_in[10];
    const int* down1  = (const int*)d_in[11];
    const int* nbr1   = (const int*)d_in[12];

    int N0 = in_sizes[0] / 4;
    int N1 = in_sizes[11] / 8;

    // ws layout (bf16 buffers as unsigned short)
    unsigned short* yraw = (unsigned short*)d_ws;            // N0*32
    unsigned short* actA = yraw + (size_t)N0 * 32;           // N0*32
    unsigned short* actB = actA + (size_t)N0 * 32;           // N0*32
    unsigned short* xb   = actB + (size_t)N0 * 32;           // N0*4
    unsigned short* wp   = xb + (size_t)N0 * 4;              // packed weights
    const size_t o_s1  = 0;                 // 512*8  = 4096
    const size_t o_s2  = o_s1 + 4096;       // 27*1024
    const size_t o_dn  = o_s2 + 27 * 1024;  // 8*1024
    const size_t o_r1a = o_dn + 8 * 1024;
    const size_t o_r1b = o_r1a + 27 * 1024;
    const size_t o_r2a = o_r1b + 27 * 1024;
    const size_t o_r2b = o_r2a + 27 * 1024;
    float* part  = (float*)(wp + o_r2b + 27 * 1024);         // <=3200 blocks * 64
    float* stats = part + (size_t)3200 * 64;                 // 64 fp32

    auto g1 = [](int n) { return dim3((unsigned)((n + 255) / 256)); };
    auto gm = [](int n) { return dim3((unsigned)((n + 127) / 128)); };
    int nb0 = (N0 + 127) / 128, nb1 = (N1 + 127) / 128;

    cvt_kernel<<<g1(N0), 256, 0, stream>>>(vf, xb, N0);
    pack_w1_kernel<<<2, 256, 0, stream>>>(Ws1, wp + o_s1);
    pack_w_kernel<<<(27 * 128 + 255) / 256, 256, 0, stream>>>(Ws2,  wp + o_s2,  27);
    pack_w_kernel<<<(8  * 128 + 255) / 256, 256, 0, stream>>>(Wd,   wp + o_dn,  8);
    pack_w_kernel<<<(27 * 128 + 255) / 256, 256, 0, stream>>>(Wr1a, wp + o_r1a, 27);
    pack_w_kernel<<<(27 * 128 + 255) / 256, 256, 0, stream>>>(Wr1b, wp + o_r1b, 27);
    pack_w_kernel<<<(27 * 128 + 255) / 256, 256, 0, stream>>>(Wr2a, wp + o_r2a, 27);
    pack_w_kernel<<<(27 * 128 + 255) / 256, 256, 0, stream>>>(Wr2b, wp + o_r2b, 27);

    // stem1: xb -> yraw; act -> actA
    conv_stem1_mfma<<<gm(N0), 256, 0, stream>>>(xb, nbr0, wp + o_s1, yraw, part, N0);
    reduce_stats_kernel<<<1, 256, 0, stream>>>(part, stats, nb0);
    bn_relu_kernel<false, false><<<g1(N0), 256, 0, stream>>>(yraw, stats, gam + 0, bet + 0, nullptr, actA, N0);
    // stem2: actA -> yraw; act -> actB
    conv_mfma_kernel<27><<<gm(N0), 256, 0, stream>>>(actA, nbr0, wp + o_s2, yraw, part, N0);
    reduce_stats_kernel<<<1, 256, 0, stream>>>(part, stats, nb0);
    bn_relu_kernel<false, false><<<g1(N0), 256, 0, stream>>>(yraw, stats, gam + 32, bet + 32, nullptr, actB, N0);
    // down: actB (N0 rows) -> yraw (N1); x1 -> actA
    conv_mfma_kernel<8><<<gm(N1), 256, 0, stream>>>(actB, down1, wp + o_dn, yraw, part, N1);
    reduce_stats_kernel<<<1, 256, 0, stream>>>(part, stats, nb1);
    bn_relu_kernel<false, false><<<g1(N1), 256, 0, stream>>>(yraw, stats, gam + 64, bet + 64, nullptr, actA, N1);
    // r1a: actA -> yraw; h -> actB
    conv_mfma_kernel<27><<<gm(N1), 256, 0, stream>>>(actA, nbr1, wp + o_r1a, yraw, part, N1);
    reduce_stats_kernel<<<1, 256, 0, stream>>>(part, stats, nb1);
    bn_relu_kernel<false, false><<<g1(N1), 256, 0, stream>>>(yraw, stats, gam + 96, bet + 96, nullptr, actB, N1);
    // r1b: actB -> yraw; x1' = relu(bn(yraw) + actA) -> actB
    conv_mfma_kernel<27><<<gm(N1), 256, 0, stream>>>(actB, nbr1, wp + o_r1b, yraw, part, N1);
    reduce_stats_kernel<<<1, 256, 0, stream>>>(part, stats, nb1);
    bn_relu_kernel<false, true><<<g1(N1), 256, 0, stream>>>(yraw, stats, gam + 128, bet + 128, actA, actB, N1);
    // r2a: actB -> yraw; h2 -> actA
    conv_mfma_kernel<27><<<gm(N1), 256, 0, stream>>>(actB, nbr1, wp + o_r2a, yraw, part, N1);
    reduce_stats_kernel<<<1, 256, 0, stream>>>(part, stats, nb1);
    bn_relu_kernel<false, false><<<g1(N1), 256, 0, stream>>>(yraw, stats, gam + 160, bet + 160, nullptr, actA, N1);
    // r2b: actA -> yraw; out = relu(bn(yraw) + actB) -> d_out (fp32)
    conv_mfma_kernel<27><<<gm(N1), 256, 0, stream>>>(actA, nbr1, wp + o_r2b, yraw, part, N1);
    reduce_stats_kernel<<<1, 256, 0, stream>>>(part, stats, nb1);
    bn_relu_kernel<true, true><<<g1(N1), 256, 0, stream>>>(yraw, stats, gam + 192, bet + 192, actB, d_out, N1);
}

// Round 7
// 690.452 us; speedup vs baseline: 23.4539x; 2.4479x over previous
//
#include <hip/hip_runtime.h>

#define EPS 1e-5f

typedef __attribute__((ext_vector_type(8))) short short8;            // 8 bf16 MFMA frag
typedef __attribute__((ext_vector_type(4))) float floatx4;           // MFMA C/D frag
typedef __attribute__((ext_vector_type(8))) unsigned short ushort8;
typedef __attribute__((ext_vector_type(4))) unsigned short ushortv4;

// bf16 <-> f32 (RTNE)
__device__ __forceinline__ unsigned short f2bf(float f) {
    union { float f; unsigned u; } x; x.f = f;
    unsigned r = x.u + 0x7fffu + ((x.u >> 16) & 1u);
    return (unsigned short)(r >> 16);
}
__device__ __forceinline__ float bf2f(unsigned short b) {
    union { unsigned u; float f; } x; x.u = ((unsigned)b) << 16;
    return x.f;
}

// ---------------------------------------------------------------------------
// vf fp32 [N][4] -> bf16 [N][4]
__global__ __launch_bounds__(256) void cvt_kernel(
    const float* __restrict__ x, unsigned short* __restrict__ o, int N)
{
    int t = blockIdx.x * 256 + threadIdx.x;
    if (t >= N) return;
    float4 v = *(const float4*)(x + (size_t)t * 4);
    ushortv4 r = {f2bf(v.x), f2bf(v.y), f2bf(v.z), f2bf(v.w)};
    *(ushortv4*)(o + (size_t)t * 4) = r;
}

// ---------------------------------------------------------------------------
// Weight pack (CI=32 convs): W[k][ci][co] fp32 -> B-frag order, 16x16x32 bf16.
// out[((k*2+h)*64 + lane)*8 + j] = bf16(W[k][(lane>>4)*8 + j][h*16 + (lane&15)])
__global__ __launch_bounds__(256) void pack_w_kernel(
    const float* __restrict__ W, unsigned short* __restrict__ out, int K)
{
    int t = blockIdx.x * 256 + threadIdx.x;
    if (t >= K * 128) return;
    int lane = t & 63;
    int h = (t >> 6) & 1;
    int k = t >> 7;
    int m = lane & 15, q = lane >> 4;
    ushort8 v;
#pragma unroll
    for (int j = 0; j < 8; ++j)
        v[j] = f2bf(W[((size_t)k * 32 + q * 8 + j) * 32 + h * 16 + m]);
    *(ushort8*)(out + (size_t)t * 8) = v;
}

// Weight pack for stem1: W[27][4][32], kdim = tap*4+ci folded to 4 chunks of K=32,
// taps 27..31 zero-padded. out[((c*2+h)*64 + lane)*8 + j].
__global__ __launch_bounds__(256) void pack_w1_kernel(
    const float* __restrict__ W, unsigned short* __restrict__ out)
{
    int t = blockIdx.x * 256 + threadIdx.x;
    if (t >= 512) return;  // 4 chunks * 2 halves * 64 lanes
    int lane = t & 63;
    int h = (t >> 6) & 1;
    int c = t >> 7;
    int m = lane & 15, q = lane >> 4;
    ushort8 v;
#pragma unroll
    for (int j = 0; j < 8; ++j) {
        int kdim = c * 32 + q * 8 + j;
        int tap = kdim >> 2, ci = kdim & 3;
        v[j] = (tap < 27) ? f2bf(W[((size_t)tap * 4 + ci) * 32 + h * 16 + m]) : 0;
    }
    *(ushort8*)(out + (size_t)t * 8) = v;
}

// ---------------------------------------------------------------------------
// Shared epilogue: C-layout stores (bf16) + BN partial sums -> LDS -> part[block].
// acc layout (16x16x32, guide-verified): col = lane&15, row-in-tile = (lane>>4)*4 + r.
__device__ __forceinline__ void conv_epilogue(
    floatx4 acc00, floatx4 acc01, floatx4 acc10, floatx4 acc11,
    unsigned short* __restrict__ y, float* __restrict__ part,
    int rowbase, int N, float* sm)
{
    const int lane = threadIdx.x & 63;
    const int m = lane & 15, q = lane >> 4;

    if (threadIdx.x < 64) sm[threadIdx.x] = 0.f;
    __syncthreads();

#pragma unroll
    for (int r = 0; r < 4; ++r) {
        int ra = rowbase + q * 4 + r;
        int rb = ra + 16;
        if (ra < N) {
            y[(size_t)ra * 32 + m]      = f2bf(acc00[r]);
            y[(size_t)ra * 32 + 16 + m] = f2bf(acc01[r]);
        }
        if (rb < N) {
            y[(size_t)rb * 32 + m]      = f2bf(acc10[r]);
            y[(size_t)rb * 32 + 16 + m] = f2bf(acc11[r]);
        }
    }

    float s0 = 0.f, q0 = 0.f, s1 = 0.f, q1 = 0.f;
#pragma unroll
    for (int r = 0; r < 4; ++r) {
        s0 += acc00[r] + acc10[r];
        q0 += acc00[r] * acc00[r] + acc10[r] * acc10[r];
        s1 += acc01[r] + acc11[r];
        q1 += acc01[r] * acc01[r] + acc11[r] * acc11[r];
    }
    s0 += __shfl_down(s0, 32); s0 += __shfl_down(s0, 16);
    q0 += __shfl_down(q0, 32); q0 += __shfl_down(q0, 16);
    s1 += __shfl_down(s1, 32); s1 += __shfl_down(s1, 16);
    q1 += __shfl_down(q1, 32); q1 += __shfl_down(q1, 16);
    if (lane < 16) {
        atomicAdd(&sm[m],      s0);
        atomicAdd(&sm[32 + m], q0);
        atomicAdd(&sm[16 + m],      s1);
        atomicAdd(&sm[48 + m], q1);
    }
    __syncthreads();
    if (threadIdx.x < 64)
        part[(size_t)blockIdx.x * 64 + threadIdx.x] = sm[threadIdx.x];
}

// ---------------------------------------------------------------------------
// MFMA sparse conv (CI=32): per tap, C[rows,32] += gather(A)[rows,32] @ Wk[32,32].
// 256 thr = 4 waves; wave covers 32 rows (2 tiles) x 32 co (2 halves) = 4 accs.
template <int K>
__global__ __launch_bounds__(256) void conv_mfma_kernel(
    const unsigned short* __restrict__ x,   // [Nx][32] bf16
    const int* __restrict__ nbr,            // [K][N]
    const unsigned short* __restrict__ Wp,  // packed [K][2][64][8]
    unsigned short* __restrict__ y,         // [N][32] bf16
    float* __restrict__ part, int N)
{
    __shared__ float sm[64];
    const int lane = threadIdx.x & 63;
    const int wave = threadIdx.x >> 6;
    const int m = lane & 15, q = lane >> 4;
    const int rowbase = blockIdx.x * 128 + wave * 32;
    const int row0 = rowbase + m;
    const int row1 = rowbase + 16 + m;

    floatx4 acc00 = {0.f, 0.f, 0.f, 0.f};
    floatx4 acc01 = acc00, acc10 = acc00, acc11 = acc00;

    for (int k = 0; k < K; ++k) {
        int i0 = (row0 < N) ? nbr[(size_t)k * N + row0] : -1;
        int i1 = (row1 < N) ? nbr[(size_t)k * N + row1] : -1;
        short8 a0 = {}, a1 = {};
        if (i0 >= 0) a0 = *(const short8*)(x + (size_t)i0 * 32 + q * 8);
        if (i1 >= 0) a1 = *(const short8*)(x + (size_t)i1 * 32 + q * 8);
        const short8* wk = (const short8*)(Wp + (size_t)k * 2 * 64 * 8);
        short8 b0 = wk[lane];
        short8 b1 = wk[64 + lane];
        acc00 = __builtin_amdgcn_mfma_f32_16x16x32_bf16(a0, b0, acc00, 0, 0, 0);
        acc01 = __builtin_amdgcn_mfma_f32_16x16x32_bf16(a0, b1, acc01, 0, 0, 0);
        acc10 = __builtin_amdgcn_mfma_f32_16x16x32_bf16(a1, b0, acc10, 0, 0, 0);
        acc11 = __builtin_amdgcn_mfma_f32_16x16x32_bf16(a1, b1, acc11, 0, 0, 0);
    }

    conv_epilogue(acc00, acc01, acc10, acc11, y, part, rowbase, N, sm);
}

// ---------------------------------------------------------------------------
// stem1 as MFMA: CI=4, 27 taps folded into kdim = tap*4+ci, 4 chunks of K=32.
// Lane (q,m) in chunk c gathers taps t0=c*8+q*2 and t0+1 (4 bf16 = 8B each).
__global__ __launch_bounds__(256) void conv_stem1_mfma(
    const unsigned short* __restrict__ xb,  // [N][4] bf16
    const int* __restrict__ nbr,            // [27][N]
    const unsigned short* __restrict__ Wp,  // packed [4][2][64][8]
    unsigned short* __restrict__ y,         // [N][32] bf16
    float* __restrict__ part, int N)
{
    __shared__ float sm[64];
    const int lane = threadIdx.x & 63;
    const int wave = threadIdx.x >> 6;
    const int m = lane & 15, q = lane >> 4;
    const int rowbase = blockIdx.x * 128 + wave * 32;
    const int row0 = rowbase + m;
    const int row1 = rowbase + 16 + m;

    floatx4 acc00 = {0.f, 0.f, 0.f, 0.f};
    floatx4 acc01 = acc00, acc10 = acc00, acc11 = acc00;

#pragma unroll
    for (int c = 0; c < 4; ++c) {
        const int t0 = c * 8 + q * 2, t1 = t0 + 1;
        short8 a0 = {}, a1 = {};
        {
            int ia = (t0 < 27 && row0 < N) ? nbr[(size_t)t0 * N + row0] : -1;
            int ib = (t1 < 27 && row0 < N) ? nbr[(size_t)t1 * N + row0] : -1;
            ushortv4 ga = {}, gb = {};
            if (ia >= 0) ga = *(const ushortv4*)(xb + (size_t)ia * 4);
            if (ib >= 0) gb = *(const ushortv4*)(xb + (size_t)ib * 4);
            a0[0] = (short)ga[0]; a0[1] = (short)ga[1];
            a0[2] = (short)ga[2]; a0[3] = (short)ga[3];
            a0[4] = (short)gb[0]; a0[5] = (short)gb[1];
            a0[6] = (short)gb[2]; a0[7] = (short)gb[3];
        }
        {
            int ia = (t0 < 27 && row1 < N) ? nbr[(size_t)t0 * N + row1] : -1;
            int ib = (t1 < 27 && row1 < N) ? nbr[(size_t)t1 * N + row1] : -1;
            ushortv4 ga = {}, gb = {};
            if (ia >= 0) ga = *(const ushortv4*)(xb + (size_t)ia * 4);
            if (ib >= 0) gb = *(const ushortv4*)(xb + (size_t)ib * 4);
            a1[0] = (short)ga[0]; a1[1] = (short)ga[1];
            a1[2] = (short)ga[2]; a1[3] = (short)ga[3];
            a1[4] = (short)gb[0]; a1[5] = (short)gb[1];
            a1[6] = (short)gb[2]; a1[7] = (short)gb[3];
        }
        const short8* wk = (const short8*)Wp;
        short8 b0 = wk[(c * 2 + 0) * 64 + lane];
        short8 b1 = wk[(c * 2 + 1) * 64 + lane];
        acc00 = __builtin_amdgcn_mfma_f32_16x16x32_bf16(a0, b0, acc00, 0, 0, 0);
        acc01 = __builtin_amdgcn_mfma_f32_16x16x32_bf16(a0, b1, acc01, 0, 0, 0);
        acc10 = __builtin_amdgcn_mfma_f32_16x16x32_bf16(a1, b0, acc10, 0, 0, 0);
        acc11 = __builtin_amdgcn_mfma_f32_16x16x32_bf16(a1, b1, acc11, 0, 0, 0);
    }

    conv_epilogue(acc00, acc01, acc10, acc11, y, part, rowbase, N, sm);
}

// ---------------------------------------------------------------------------
// Parallel stat reduction: part[nb][64] -> atomicAdd into stats[64] (pre-zeroed).
// 64 blocks x 256 thr; block b sums rows {b*4+g + 256*i}; coalesced (lane->channel).
// Only 64 same-address atomics per channel -- negligible contention.
__global__ __launch_bounds__(256) void reduce_stats_kernel(
    const float* __restrict__ part, float* __restrict__ stats, int nb)
{
    __shared__ float sm[256];
    int t = threadIdx.x;
    int c = t & 63, g = t >> 6;
    float s = 0.f;
    for (int b = blockIdx.x * 4 + g; b < nb; b += 256)
        s += part[(size_t)b * 64 + c];
    sm[t] = s;
    __syncthreads();
    if (t < 64)
        atomicAdd(&stats[t], sm[t] + sm[64 + t] + sm[128 + t] + sm[192 + t]);
}

// ---------------------------------------------------------------------------
// BN (+optional bf16 residual) + ReLU. bf16 in; bf16 or fp32 out.
template <bool OUT_F32, bool HAS_RES>
__global__ __launch_bounds__(256) void bn_relu_kernel(
    const unsigned short* __restrict__ y, const float* __restrict__ stats,
    const float* __restrict__ gamma, const float* __restrict__ beta,
    const unsigned short* __restrict__ resid, void* __restrict__ outp, int N)
{
    int t = blockIdx.x * 256 + threadIdx.x;
    if (t >= N) return;
    float inv_n = 1.0f / (float)N;
    const ushort8* yr = (const ushort8*)(y + (size_t)t * 32);

#pragma unroll
    for (int c = 0; c < 4; ++c) {
        ushort8 v = yr[c];
        ushort8 rv = {};
        if (HAS_RES) rv = ((const ushort8*)(resid + (size_t)t * 32))[c];
        float f0, f1, f2, f3, f4, f5, f6, f7;
#define BNJ(fj, j)                                                        \
        {                                                                 \
            int co = c * 8 + (j);                                         \
            float mu = stats[co] * inv_n;                                 \
            float var = stats[32 + co] * inv_n - mu * mu;                 \
            float sc = rsqrtf(var + EPS) * gamma[co];                     \
            fj = (bf2f(v[j]) - mu) * sc + beta[co];                       \
            if (HAS_RES) fj += bf2f(rv[j]);                               \
            fj = fmaxf(fj, 0.0f);                                         \
        }
        BNJ(f0, 0) BNJ(f1, 1) BNJ(f2, 2) BNJ(f3, 3)
        BNJ(f4, 4) BNJ(f5, 5) BNJ(f6, 6) BNJ(f7, 7)
#undef BNJ
        if (OUT_F32) {
            float* ob = (float*)outp + (size_t)t * 32 + c * 8;
            floatx4 u0 = {f0, f1, f2, f3}, u1 = {f4, f5, f6, f7};
            *(floatx4*)(ob) = u0;
            *(floatx4*)(ob + 4) = u1;
        } else {
            ushort8 o;
            o[0] = f2bf(f0); o[1] = f2bf(f1); o[2] = f2bf(f2); o[3] = f2bf(f3);
            o[4] = f2bf(f4); o[5] = f2bf(f5); o[6] = f2bf(f6); o[7] = f2bf(f7);
            ((ushort8*)((unsigned short*)outp + (size_t)t * 32))[c] = o;
        }
    }
}

// ---------------------------------------------------------------------------
extern "C" void kernel_launch(void* const* d_in, const int* in_sizes, int n_in,
                              void* d_out, int out_size, void* d_ws, size_t ws_size,
                              hipStream_t stream)
{
    const float* vf   = (const float*)d_in[0];
    const float* Ws1  = (const float*)d_in[1];
    const float* Ws2  = (const float*)d_in[2];
    const float* Wd   = (const float*)d_in[3];
    const float* Wr1a = (const float*)d_in[4];
    const float* Wr1b = (const float*)d_in[5];
    const float* Wr2a = (const float*)d_in[6];
    const float* Wr2b = (const float*)d_in[7];
    const float* gam  = (const float*)d_in[8];
    const float* bet  = (const float*)d_in[9];
    const int* nbr0   = (const int*)d_in[10];
    const int* down1  = (const int*)d_in[11];
    const int* nbr1   = (const int*)d_in[12];

    int N0 = in_sizes[0] / 4;
    int N1 = in_sizes[11] / 8;

    // ws layout (bf16 buffers as unsigned short)
    unsigned short* yraw = (unsigned short*)d_ws;            // N0*32
    unsigned short* actA = yraw + (size_t)N0 * 32;           // N0*32
    unsigned short* actB = actA + (size_t)N0 * 32;           // N0*32
    unsigned short* xb   = actB + (size_t)N0 * 32;           // N0*4
    unsigned short* wp   = xb + (size_t)N0 * 4;              // packed weights
    const size_t o_s1  = 0;                 // 512*8  = 4096
    const size_t o_s2  = o_s1 + 4096;       // 27*1024
    const size_t o_dn  = o_s2 + 27 * 1024;  // 8*1024
    const size_t o_r1a = o_dn + 8 * 1024;
    const size_t o_r1b = o_r1a + 27 * 1024;
    const size_t o_r2a = o_r1b + 27 * 1024;
    const size_t o_r2b = o_r2a + 27 * 1024;
    float* part  = (float*)(wp + o_r2b + 27 * 1024);         // <=3200 blocks * 64
    float* stats = part + (size_t)3200 * 64;                 // 7*64 fp32

    hipMemsetAsync(stats, 0, 7 * 64 * sizeof(float), stream);

    auto g1 = [](int n) { return dim3((unsigned)((n + 255) / 256)); };
    auto gm = [](int n) { return dim3((unsigned)((n + 127) / 128)); };
    int nb0 = (N0 + 127) / 128, nb1 = (N1 + 127) / 128;

    cvt_kernel<<<g1(N0), 256, 0, stream>>>(vf, xb, N0);
    pack_w1_kernel<<<2, 256, 0, stream>>>(Ws1, wp + o_s1);
    pack_w_kernel<<<(27 * 128 + 255) / 256, 256, 0, stream>>>(Ws2,  wp + o_s2,  27);
    pack_w_kernel<<<(8  * 128 + 255) / 256, 256, 0, stream>>>(Wd,   wp + o_dn,  8);
    pack_w_kernel<<<(27 * 128 + 255) / 256, 256, 0, stream>>>(Wr1a, wp + o_r1a, 27);
    pack_w_kernel<<<(27 * 128 + 255) / 256, 256, 0, stream>>>(Wr1b, wp + o_r1b, 27);
    pack_w_kernel<<<(27 * 128 + 255) / 256, 256, 0, stream>>>(Wr2a, wp + o_r2a, 27);
    pack_w_kernel<<<(27 * 128 + 255) / 256, 256, 0, stream>>>(Wr2b, wp + o_r2b, 27);

    // stem1: xb -> yraw; act -> actA
    conv_stem1_mfma<<<gm(N0), 256, 0, stream>>>(xb, nbr0, wp + o_s1, yraw, part, N0);
    reduce_stats_kernel<<<64, 256, 0, stream>>>(part, stats + 0 * 64, nb0);
    bn_relu_kernel<false, false><<<g1(N0), 256, 0, stream>>>(yraw, stats + 0 * 64, gam + 0, bet + 0, nullptr, actA, N0);
    // stem2: actA -> yraw; act -> actB
    conv_mfma_kernel<27><<<gm(N0), 256, 0, stream>>>(actA, nbr0, wp + o_s2, yraw, part, N0);
    reduce_stats_kernel<<<64, 256, 0, stream>>>(part, stats + 1 * 64, nb0);
    bn_relu_kernel<false, false><<<g1(N0), 256, 0, stream>>>(yraw, stats + 1 * 64, gam + 32, bet + 32, nullptr, actB, N0);
    // down: actB (N0 rows) -> yraw (N1); x1 -> actA
    conv_mfma_kernel<8><<<gm(N1), 256, 0, stream>>>(actB, down1, wp + o_dn, yraw, part, N1);
    reduce_stats_kernel<<<64, 256, 0, stream>>>(part, stats + 2 * 64, nb1);
    bn_relu_kernel<false, false><<<g1(N1), 256, 0, stream>>>(yraw, stats + 2 * 64, gam + 64, bet + 64, nullptr, actA, N1);
    // r1a: actA -> yraw; h -> actB
    conv_mfma_kernel<27><<<gm(N1), 256, 0, stream>>>(actA, nbr1, wp + o_r1a, yraw, part, N1);
    reduce_stats_kernel<<<64, 256, 0, stream>>>(part, stats + 3 * 64, nb1);
    bn_relu_kernel<false, false><<<g1(N1), 256, 0, stream>>>(yraw, stats + 3 * 64, gam + 96, bet + 96, nullptr, actB, N1);
    // r1b: actB -> yraw; x1' = relu(bn(yraw) + actA) -> actB
    conv_mfma_kernel<27><<<gm(N1), 256, 0, stream>>>(actB, nbr1, wp + o_r1b, yraw, part, N1);
    reduce_stats_kernel<<<64, 256, 0, stream>>>(part, stats + 4 * 64, nb1);
    bn_relu_kernel<false, true><<<g1(N1), 256, 0, stream>>>(yraw, stats + 4 * 64, gam + 128, bet + 128, actA, actB, N1);
    // r2a: actB -> yraw; h2 -> actA
    conv_mfma_kernel<27><<<gm(N1), 256, 0, stream>>>(actB, nbr1, wp + o_r2a, yraw, part, N1);
    reduce_stats_kernel<<<64, 256, 0, stream>>>(part, stats + 5 * 64, nb1);
    bn_relu_kernel<false, false><<<g1(N1), 256, 0, stream>>>(yraw, stats + 5 * 64, gam + 160, bet + 160, nullptr, actA, N1);
    // r2b: actA -> yraw; out = relu(bn(yraw) + actB) -> d_out (fp32)
    conv_mfma_kernel<27><<<gm(N1), 256, 0, stream>>>(actA, nbr1, wp + o_r2b, yraw, part, N1);
    reduce_stats_kernel<<<64, 256, 0, stream>>>(part, stats + 6 * 64, nb1);
    bn_relu_kernel<true, true><<<g1(N1), 256, 0, stream>>>(yraw, stats + 6 * 64, gam + 192, bet + 192, actB, d_out, N1);
}

// Round 8
// 632.748 us; speedup vs baseline: 25.5928x; 1.0912x over previous
//
#include <hip/hip_runtime.h>

#define EPS 1e-5f

typedef __attribute__((ext_vector_type(8))) short short8;            // 8 bf16 MFMA frag
typedef __attribute__((ext_vector_type(4))) float floatx4;           // MFMA C/D frag
typedef __attribute__((ext_vector_type(8))) unsigned short ushort8;
typedef __attribute__((ext_vector_type(4))) unsigned short ushortv4;

// packed-weight element offsets (compile-time)
#define O_S1  0
#define O_S2  4096
#define O_DN  (O_S2 + 27648)
#define O_R1A (O_DN + 8192)
#define O_R1B (O_R1A + 27648)
#define O_R2A (O_R1B + 27648)
#define O_R2B (O_R2A + 27648)
#define WP_TOTAL (O_R2B + 27648)

// bf16 <-> f32 (RTNE)
__device__ __forceinline__ unsigned short f2bf(float f) {
    union { float f; unsigned u; } x; x.f = f;
    unsigned r = x.u + 0x7fffu + ((x.u >> 16) & 1u);
    return (unsigned short)(r >> 16);
}
__device__ __forceinline__ float bf2f(unsigned short b) {
    union { unsigned u; float f; } x; x.u = ((unsigned)b) << 16;
    return x.f;
}

// XCD-aware block remap: contiguous logical spans per XCD (blockIdx%8 == XCD
// heuristic; exact bijection, so correctness never depends on it).
__device__ __forceinline__ int xcd_swizzle(int nb) {
    int b = (int)blockIdx.x;
    int q = nb >> 3, r = nb & 7;
    int x = b & 7, i = b >> 3;
    return x * q + (x < r ? x : r) + i;
}

// ---------------------------------------------------------------------------
// One fused prep launch: cvt vf->bf16, pack stem1 W, pack six CI=32 W sets.
__device__ __forceinline__ void pack_w_one(
    const float* __restrict__ W, unsigned short* __restrict__ out, int t)
{
    int lane = t & 63;
    int h = (t >> 6) & 1;
    int k = t >> 7;
    int m = lane & 15, q = lane >> 4;
    ushort8 v;
#pragma unroll
    for (int j = 0; j < 8; ++j)
        v[j] = f2bf(W[((size_t)k * 32 + q * 8 + j) * 32 + h * 16 + m]);
    *(ushort8*)(out + (size_t)t * 8) = v;
}

__global__ __launch_bounds__(256) void prep_kernel(
    const float* __restrict__ vf,
    const float* __restrict__ Ws1, const float* __restrict__ Ws2,
    const float* __restrict__ Wd,  const float* __restrict__ Wr1a,
    const float* __restrict__ Wr1b, const float* __restrict__ Wr2a,
    const float* __restrict__ Wr2b,
    unsigned short* __restrict__ xb, unsigned short* __restrict__ wp, int N0)
{
    int t = blockIdx.x * 256 + threadIdx.x;
    if (t < N0) {                                   // cvt vf -> bf16
        float4 v = *(const float4*)(vf + (size_t)t * 4);
        ushortv4 r = {f2bf(v.x), f2bf(v.y), f2bf(v.z), f2bf(v.w)};
        *(ushortv4*)(xb + (size_t)t * 4) = r;
        return;
    }
    t -= N0;
    if (t < 512) {                                  // stem1 pack (taps folded into K)
        int lane = t & 63;
        int h = (t >> 6) & 1;
        int c = t >> 7;
        int m = lane & 15, q = lane >> 4;
        ushort8 v;
#pragma unroll
        for (int j = 0; j < 8; ++j) {
            int kdim = c * 32 + q * 8 + j;
            int tap = kdim >> 2, ci = kdim & 3;
            v[j] = (tap < 27) ? f2bf(Ws1[((size_t)tap * 4 + ci) * 32 + h * 16 + m]) : 0;
        }
        *(ushort8*)(wp + O_S1 + (size_t)t * 8) = v;
        return;
    }
    t -= 512;
    if (t < 27 * 128) { pack_w_one(Ws2,  wp + O_S2,  t); return; }
    t -= 27 * 128;
    if (t < 8 * 128)  { pack_w_one(Wd,   wp + O_DN,  t); return; }
    t -= 8 * 128;
    if (t < 27 * 128) { pack_w_one(Wr1a, wp + O_R1A, t); return; }
    t -= 27 * 128;
    if (t < 27 * 128) { pack_w_one(Wr1b, wp + O_R1B, t); return; }
    t -= 27 * 128;
    if (t < 27 * 128) { pack_w_one(Wr2a, wp + O_R2A, t); return; }
    t -= 27 * 128;
    if (t < 27 * 128) { pack_w_one(Wr2b, wp + O_R2B, t); return; }
}

// ---------------------------------------------------------------------------
// Shared epilogue: C-layout stores (bf16) + BN partial sums -> LDS -> part[lb].
// acc layout (16x16x32, guide-verified): col = lane&15, row-in-tile = (lane>>4)*4 + r.
__device__ __forceinline__ void conv_epilogue(
    floatx4 acc00, floatx4 acc01, floatx4 acc10, floatx4 acc11,
    unsigned short* __restrict__ y, float* __restrict__ part,
    int rowbase, int lb, int N, float* sm)
{
    const int lane = threadIdx.x & 63;
    const int m = lane & 15, q = lane >> 4;

    if (threadIdx.x < 64) sm[threadIdx.x] = 0.f;
    __syncthreads();

#pragma unroll
    for (int r = 0; r < 4; ++r) {
        int ra = rowbase + q * 4 + r;
        int rb = ra + 16;
        if (ra < N) {
            y[(size_t)ra * 32 + m]      = f2bf(acc00[r]);
            y[(size_t)ra * 32 + 16 + m] = f2bf(acc01[r]);
        }
        if (rb < N) {
            y[(size_t)rb * 32 + m]      = f2bf(acc10[r]);
            y[(size_t)rb * 32 + 16 + m] = f2bf(acc11[r]);
        }
    }

    float s0 = 0.f, q0 = 0.f, s1 = 0.f, q1 = 0.f;
#pragma unroll
    for (int r = 0; r < 4; ++r) {
        s0 += acc00[r] + acc10[r];
        q0 += acc00[r] * acc00[r] + acc10[r] * acc10[r];
        s1 += acc01[r] + acc11[r];
        q1 += acc01[r] * acc01[r] + acc11[r] * acc11[r];
    }
    s0 += __shfl_down(s0, 32); s0 += __shfl_down(s0, 16);
    q0 += __shfl_down(q0, 32); q0 += __shfl_down(q0, 16);
    s1 += __shfl_down(s1, 32); s1 += __shfl_down(s1, 16);
    q1 += __shfl_down(q1, 32); q1 += __shfl_down(q1, 16);
    if (lane < 16) {
        atomicAdd(&sm[m],      s0);
        atomicAdd(&sm[32 + m], q0);
        atomicAdd(&sm[16 + m],      s1);
        atomicAdd(&sm[48 + m], q1);
    }
    __syncthreads();
    if (threadIdx.x < 64)
        part[(size_t)lb * 64 + threadIdx.x] = sm[threadIdx.x];
}

// ---------------------------------------------------------------------------
// MFMA sparse conv (CI=32): per tap, C[rows,32] += gather(A)[rows,32] @ Wk[32,32].
// 256 thr = 4 waves; wave covers 32 rows (2 tiles) x 32 co (2 halves) = 4 accs.
template <int K>
__global__ __launch_bounds__(256) void conv_mfma_kernel(
    const unsigned short* __restrict__ x,   // [Nx][32] bf16
    const int* __restrict__ nbr,            // [K][N]
    const unsigned short* __restrict__ Wp,  // packed [K][2][64][8]
    unsigned short* __restrict__ y,         // [N][32] bf16
    float* __restrict__ part, int N)
{
    __shared__ float sm[64];
    const int nb = (N + 127) / 128;
    const int lb = xcd_swizzle(nb);
    const int lane = threadIdx.x & 63;
    const int wave = threadIdx.x >> 6;
    const int m = lane & 15, q = lane >> 4;
    const int rowbase = lb * 128 + wave * 32;
    const int row0 = rowbase + m;
    const int row1 = rowbase + 16 + m;

    floatx4 acc00 = {0.f, 0.f, 0.f, 0.f};
    floatx4 acc01 = acc00, acc10 = acc00, acc11 = acc00;

    for (int k = 0; k < K; ++k) {
        int i0 = (row0 < N) ? nbr[(size_t)k * N + row0] : -1;
        int i1 = (row1 < N) ? nbr[(size_t)k * N + row1] : -1;
        short8 a0 = {}, a1 = {};
        if (i0 >= 0) a0 = *(const short8*)(x + (size_t)i0 * 32 + q * 8);
        if (i1 >= 0) a1 = *(const short8*)(x + (size_t)i1 * 32 + q * 8);
        const short8* wk = (const short8*)(Wp + (size_t)k * 2 * 64 * 8);
        short8 b0 = wk[lane];
        short8 b1 = wk[64 + lane];
        acc00 = __builtin_amdgcn_mfma_f32_16x16x32_bf16(a0, b0, acc00, 0, 0, 0);
        acc01 = __builtin_amdgcn_mfma_f32_16x16x32_bf16(a0, b1, acc01, 0, 0, 0);
        acc10 = __builtin_amdgcn_mfma_f32_16x16x32_bf16(a1, b0, acc10, 0, 0, 0);
        acc11 = __builtin_amdgcn_mfma_f32_16x16x32_bf16(a1, b1, acc11, 0, 0, 0);
    }

    conv_epilogue(acc00, acc01, acc10, acc11, y, part, rowbase, lb, N, sm);
}

// ---------------------------------------------------------------------------
// stem1 as MFMA: CI=4, 27 taps folded into kdim = tap*4+ci, 4 chunks of K=32.
__global__ __launch_bounds__(256) void conv_stem1_mfma(
    const unsigned short* __restrict__ xb,  // [N][4] bf16
    const int* __restrict__ nbr,            // [27][N]
    const unsigned short* __restrict__ Wp,  // packed [4][2][64][8]
    unsigned short* __restrict__ y,         // [N][32] bf16
    float* __restrict__ part, int N)
{
    __shared__ float sm[64];
    const int nb = (N + 127) / 128;
    const int lb = xcd_swizzle(nb);
    const int lane = threadIdx.x & 63;
    const int wave = threadIdx.x >> 6;
    const int m = lane & 15, q = lane >> 4;
    const int rowbase = lb * 128 + wave * 32;
    const int row0 = rowbase + m;
    const int row1 = rowbase + 16 + m;

    floatx4 acc00 = {0.f, 0.f, 0.f, 0.f};
    floatx4 acc01 = acc00, acc10 = acc00, acc11 = acc00;

#pragma unroll
    for (int c = 0; c < 4; ++c) {
        const int t0 = c * 8 + q * 2, t1 = t0 + 1;
        short8 a0 = {}, a1 = {};
        {
            int ia = (t0 < 27 && row0 < N) ? nbr[(size_t)t0 * N + row0] : -1;
            int ib = (t1 < 27 && row0 < N) ? nbr[(size_t)t1 * N + row0] : -1;
            ushortv4 ga = {}, gb = {};
            if (ia >= 0) ga = *(const ushortv4*)(xb + (size_t)ia * 4);
            if (ib >= 0) gb = *(const ushortv4*)(xb + (size_t)ib * 4);
            a0[0] = (short)ga[0]; a0[1] = (short)ga[1];
            a0[2] = (short)ga[2]; a0[3] = (short)ga[3];
            a0[4] = (short)gb[0]; a0[5] = (short)gb[1];
            a0[6] = (short)gb[2]; a0[7] = (short)gb[3];
        }
        {
            int ia = (t0 < 27 && row1 < N) ? nbr[(size_t)t0 * N + row1] : -1;
            int ib = (t1 < 27 && row1 < N) ? nbr[(size_t)t1 * N + row1] : -1;
            ushortv4 ga = {}, gb = {};
            if (ia >= 0) ga = *(const ushortv4*)(xb + (size_t)ia * 4);
            if (ib >= 0) gb = *(const ushortv4*)(xb + (size_t)ib * 4);
            a1[0] = (short)ga[0]; a1[1] = (short)ga[1];
            a1[2] = (short)ga[2]; a1[3] = (short)ga[3];
            a1[4] = (short)gb[0]; a1[5] = (short)gb[1];
            a1[6] = (short)gb[2]; a1[7] = (short)gb[3];
        }
        const short8* wk = (const short8*)Wp;
        short8 b0 = wk[(c * 2 + 0) * 64 + lane];
        short8 b1 = wk[(c * 2 + 1) * 64 + lane];
        acc00 = __builtin_amdgcn_mfma_f32_16x16x32_bf16(a0, b0, acc00, 0, 0, 0);
        acc01 = __builtin_amdgcn_mfma_f32_16x16x32_bf16(a0, b1, acc01, 0, 0, 0);
        acc10 = __builtin_amdgcn_mfma_f32_16x16x32_bf16(a1, b0, acc10, 0, 0, 0);
        acc11 = __builtin_amdgcn_mfma_f32_16x16x32_bf16(a1, b1, acc11, 0, 0, 0);
    }

    conv_epilogue(acc00, acc01, acc10, acc11, y, part, rowbase, lb, N, sm);
}

// ---------------------------------------------------------------------------
// Parallel stat reduction: part[nb][64] -> atomicAdd into stats[64] (pre-zeroed).
__global__ __launch_bounds__(256) void reduce_stats_kernel(
    const float* __restrict__ part, float* __restrict__ stats, int nb)
{
    __shared__ float sm[256];
    int t = threadIdx.x;
    int c = t & 63, g = t >> 6;
    float s = 0.f;
    for (int b = blockIdx.x * 4 + g; b < nb; b += 256)
        s += part[(size_t)b * 64 + c];
    sm[t] = s;
    __syncthreads();
    if (t < 64)
        atomicAdd(&stats[t], sm[t] + sm[64 + t] + sm[128 + t] + sm[192 + t]);
}

// ---------------------------------------------------------------------------
// BN (+optional bf16 residual) + ReLU. bf16 in; bf16 or fp32 out.
template <bool OUT_F32, bool HAS_RES>
__global__ __launch_bounds__(256) void bn_relu_kernel(
    const unsigned short* __restrict__ y, const float* __restrict__ stats,
    const float* __restrict__ gamma, const float* __restrict__ beta,
    const unsigned short* __restrict__ resid, void* __restrict__ outp, int N)
{
    int t = blockIdx.x * 256 + threadIdx.x;
    if (t >= N) return;
    float inv_n = 1.0f / (float)N;
    const ushort8* yr = (const ushort8*)(y + (size_t)t * 32);

#pragma unroll
    for (int c = 0; c < 4; ++c) {
        ushort8 v = yr[c];
        ushort8 rv = {};
        if (HAS_RES) rv = ((const ushort8*)(resid + (size_t)t * 32))[c];
        float f0, f1, f2, f3, f4, f5, f6, f7;
#define BNJ(fj, j)                                                        \
        {                                                                 \
            int co = c * 8 + (j);                                         \
            float mu = stats[co] * inv_n;                                 \
            float var = stats[32 + co] * inv_n - mu * mu;                 \
            float sc = rsqrtf(var + EPS) * gamma[co];                     \
            fj = (bf2f(v[j]) - mu) * sc + beta[co];                       \
            if (HAS_RES) fj += bf2f(rv[j]);                               \
            fj = fmaxf(fj, 0.0f);                                         \
        }
        BNJ(f0, 0) BNJ(f1, 1) BNJ(f2, 2) BNJ(f3, 3)
        BNJ(f4, 4) BNJ(f5, 5) BNJ(f6, 6) BNJ(f7, 7)
#undef BNJ
        if (OUT_F32) {
            float* ob = (float*)outp + (size_t)t * 32 + c * 8;
            floatx4 u0 = {f0, f1, f2, f3}, u1 = {f4, f5, f6, f7};
            *(floatx4*)(ob) = u0;
            *(floatx4*)(ob + 4) = u1;
        } else {
            ushort8 o;
            o[0] = f2bf(f0); o[1] = f2bf(f1); o[2] = f2bf(f2); o[3] = f2bf(f3);
            o[4] = f2bf(f4); o[5] = f2bf(f5); o[6] = f2bf(f6); o[7] = f2bf(f7);
            ((ushort8*)((unsigned short*)outp + (size_t)t * 32))[c] = o;
        }
    }
}

// ---------------------------------------------------------------------------
extern "C" void kernel_launch(void* const* d_in, const int* in_sizes, int n_in,
                              void* d_out, int out_size, void* d_ws, size_t ws_size,
                              hipStream_t stream)
{
    const float* vf   = (const float*)d_in[0];
    const float* Ws1  = (const float*)d_in[1];
    const float* Ws2  = (const float*)d_in[2];
    const float* Wd   = (const float*)d_in[3];
    const float* Wr1a = (const float*)d_in[4];
    const float* Wr1b = (const float*)d_in[5];
    const float* Wr2a = (const float*)d_in[6];
    const float* Wr2b = (const float*)d_in[7];
    const float* gam  = (const float*)d_in[8];
    const float* bet  = (const float*)d_in[9];
    const int* nbr0   = (const int*)d_in[10];
    const int* down1  = (const int*)d_in[11];
    const int* nbr1   = (const int*)d_in[12];

    int N0 = in_sizes[0] / 4;
    int N1 = in_sizes[11] / 8;

    // ws layout (bf16 buffers as unsigned short)
    unsigned short* yraw = (unsigned short*)d_ws;            // N0*32
    unsigned short* actA = yraw + (size_t)N0 * 32;           // N0*32
    unsigned short* actB = actA + (size_t)N0 * 32;           // N0*32
    unsigned short* xb   = actB + (size_t)N0 * 32;           // N0*4
    unsigned short* wp   = xb + (size_t)N0 * 4;              // packed weights
    float* part  = (float*)(wp + WP_TOTAL);                  // <=3200 blocks * 64
    float* stats = part + (size_t)3200 * 64;                 // 7*64 fp32

    hipMemsetAsync(stats, 0, 7 * 64 * sizeof(float), stream);

    auto g1 = [](int n) { return dim3((unsigned)((n + 255) / 256)); };
    auto gm = [](int n) { return dim3((unsigned)((n + 127) / 128)); };
    int nb0 = (N0 + 127) / 128, nb1 = (N1 + 127) / 128;

    int prep_threads = N0 + 512 + 128 * (27 * 5 + 8);
    prep_kernel<<<g1(prep_threads), 256, 0, stream>>>(
        vf, Ws1, Ws2, Wd, Wr1a, Wr1b, Wr2a, Wr2b, xb, wp, N0);

    // stem1: xb -> yraw; act -> actA
    conv_stem1_mfma<<<gm(N0), 256, 0, stream>>>(xb, nbr0, wp + O_S1, yraw, part, N0);
    reduce_stats_kernel<<<64, 256, 0, stream>>>(part, stats + 0 * 64, nb0);
    bn_relu_kernel<false, false><<<g1(N0), 256, 0, stream>>>(yraw, stats + 0 * 64, gam + 0, bet + 0, nullptr, actA, N0);
    // stem2: actA -> yraw; act -> actB
    conv_mfma_kernel<27><<<gm(N0), 256, 0, stream>>>(actA, nbr0, wp + O_S2, yraw, part, N0);
    reduce_stats_kernel<<<64, 256, 0, stream>>>(part, stats + 1 * 64, nb0);
    bn_relu_kernel<false, false><<<g1(N0), 256, 0, stream>>>(yraw, stats + 1 * 64, gam + 32, bet + 32, nullptr, actB, N0);
    // down: actB (N0 rows) -> yraw (N1); x1 -> actA
    conv_mfma_kernel<8><<<gm(N1), 256, 0, stream>>>(actB, down1, wp + O_DN, yraw, part, N1);
    reduce_stats_kernel<<<64, 256, 0, stream>>>(part, stats + 2 * 64, nb1);
    bn_relu_kernel<false, false><<<g1(N1), 256, 0, stream>>>(yraw, stats + 2 * 64, gam + 64, bet + 64, nullptr, actA, N1);
    // r1a: actA -> yraw; h -> actB
    conv_mfma_kernel<27><<<gm(N1), 256, 0, stream>>>(actA, nbr1, wp + O_R1A, yraw, part, N1);
    reduce_stats_kernel<<<64, 256, 0, stream>>>(part, stats + 3 * 64, nb1);
    bn_relu_kernel<false, false><<<g1(N1), 256, 0, stream>>>(yraw, stats + 3 * 64, gam + 96, bet + 96, nullptr, actB, N1);
    // r1b: actB -> yraw; x1' = relu(bn(yraw) + actA) -> actB
    conv_mfma_kernel<27><<<gm(N1), 256, 0, stream>>>(actB, nbr1, wp + O_R1B, yraw, part, N1);
    reduce_stats_kernel<<<64, 256, 0, stream>>>(part, stats + 4 * 64, nb1);
    bn_relu_kernel<false, true><<<g1(N1), 256, 0, stream>>>(yraw, stats + 4 * 64, gam + 128, bet + 128, actA, actB, N1);
    // r2a: actB -> yraw; h2 -> actA
    conv_mfma_kernel<27><<<gm(N1), 256, 0, stream>>>(actB, nbr1, wp + O_R2A, yraw, part, N1);
    reduce_stats_kernel<<<64, 256, 0, stream>>>(part, stats + 5 * 64, nb1);
    bn_relu_kernel<false, false><<<g1(N1), 256, 0, stream>>>(yraw, stats + 5 * 64, gam + 160, bet + 160, nullptr, actA, N1);
    // r2b: actA -> yraw; out = relu(bn(yraw) + actB) -> d_out (fp32)
    conv_mfma_kernel<27><<<gm(N1), 256, 0, stream>>>(actA, nbr1, wp + O_R2B, yraw, part, N1);
    reduce_stats_kernel<<<64, 256, 0, stream>>>(part, stats + 6 * 64, nb1);
    bn_relu_kernel<true, true><<<g1(N1), 256, 0, stream>>>(yraw, stats + 6 * 64, gam + 192, bet + 192, actB, d_out, N1);
}